// Round 1
// baseline (631.296 us; speedup 1.0000x reference)
//
#include <hip/hip_runtime.h>
#include <hip/hip_bf16.h>
#include <cstdint>
#include <cmath>

#define B_ 64
#define C_ 1280
#define S_ 256

typedef __attribute__((ext_vector_type(8))) short short8;
typedef __attribute__((ext_vector_type(4))) float f32x4;

typedef const __attribute__((address_space(1))) char gch;
typedef __attribute__((address_space(3))) char lch;

__device__ __forceinline__ void gload_lds16(const void* g, void* l) {
    __builtin_amdgcn_global_load_lds((gch*)g, (lch*)l, 16, 0, 0);
}

// ---------------- weight fp32 -> bf16 ----------------
__global__ void cvt_f2b(const float* __restrict__ src, __hip_bfloat16* __restrict__ dst, int n) {
    int i = blockIdx.x * blockDim.x + threadIdx.x;
    if (i < n) dst[i] = __float2bfloat16(src[i]);
}

// ---------------- x [B][C][S] fp32 -> xT [B][S][C] bf16 ----------------
__global__ void transpose_cvt(const float* __restrict__ x, __hip_bfloat16* __restrict__ xT) {
    __shared__ float tile[32][33];
    int b = blockIdx.z;
    int s0 = blockIdx.x * 32, c0 = blockIdx.y * 32;
    int tx = threadIdx.x, ty = threadIdx.y;
    const float* xb = x + (long)b * C_ * S_;
#pragma unroll
    for (int dy = 0; dy < 32; dy += 8)
        tile[ty + dy][tx] = xb[(long)(c0 + ty + dy) * S_ + s0 + tx];
    __syncthreads();
    __hip_bfloat16* xTb = xT + (long)b * S_ * C_;
#pragma unroll
    for (int dy = 0; dy < 32; dy += 8)
        xTb[(long)(s0 + ty + dy) * C_ + c0 + tx] = __float2bfloat16(tile[tx][ty + dy]);
}

// ---------------- softmax over batch axis ----------------
// scores: [64][65536] fp32 ; Abf: [64][65536] bf16
__global__ void softmax_b(const float* __restrict__ scores, __hip_bfloat16* __restrict__ Abf) {
    int tid = blockIdx.x * blockDim.x + threadIdx.x;  // 0..65535
    float r[64];
    float mx = -1e30f;
#pragma unroll
    for (int b = 0; b < 64; ++b) {
        r[b] = scores[(long)b * 65536 + tid];
        mx = fmaxf(mx, r[b]);
    }
    float sum = 0.f;
#pragma unroll
    for (int b = 0; b < 64; ++b) {
        r[b] = __expf(r[b] - mx);
        sum += r[b];
    }
    float inv = 1.0f / sum;
#pragma unroll
    for (int b = 0; b < 64; ++b)
        Abf[(long)b * 65536 + tid] = __float2bfloat16(r[b] * inv);
}

// ---------------- TN GEMM: C[m][n] = sum_k A[m][k]*B[n][k] ----------------
// A: [M][Kd] bf16 (row-major, K contiguous), B: [N][Kd] bf16, per-batch strides.
// MODE 0: C bf16 = acc
// MODE 1: C fp32 = acc * scale
// MODE 2: C fp32 = alpha*acc + X   (X same layout as C)
// Tile 128x128, BK=32, 256 threads (4 waves, 2x2), per-wave 64x64 via 4x4 of 16x16.
template <int MODE>
__global__ __launch_bounds__(256) void gemm_tn(
    const __hip_bfloat16* __restrict__ A, long aBatch,
    const __hip_bfloat16* __restrict__ Bm, long bBatch,
    void* __restrict__ Cp, long cBatch,
    int M, int N, int Kd, int tilesM, int tilesN,
    float scale, const float* __restrict__ alphaPtr,
    const float* __restrict__ X, long xBatch) {
    __shared__ __hip_bfloat16 lA[128 * 32];
    __shared__ __hip_bfloat16 lB[128 * 32];

    int tiles = tilesM * tilesN;
    int blk = blockIdx.x;
    int b = blk / tiles;
    int rem = blk - b * tiles;
    int tm = rem / tilesN;
    int tn = rem - tm * tilesN;

    int t = threadIdx.x;
    int lane = t & 63;
    int w = t >> 6;
    int wm = w >> 1, wn = w & 1;
    int lane15 = lane & 15, lhi = lane >> 4;

    const __hip_bfloat16* Ab = A + (long)b * aBatch + (long)tm * 128 * Kd;
    const __hip_bfloat16* Bb = Bm + (long)b * bBatch + (long)tn * 128 * Kd;

    f32x4 acc[4][4];
#pragma unroll
    for (int i = 0; i < 4; ++i)
#pragma unroll
        for (int j = 0; j < 4; ++j) acc[i][j] = (f32x4){0.f, 0.f, 0.f, 0.f};

    // staging decomposition: element e = t*8 within each 2048-elem (64-row) half
    int e0 = t * 8;
    int r0 = e0 >> 5;   // 0..63
    int c0e = e0 & 31;  // 0,8,16,24

    for (int k0 = 0; k0 < Kd; k0 += 32) {
        gload_lds16(Ab + (long)r0 * Kd + k0 + c0e, lA + e0);
        gload_lds16(Ab + (long)(r0 + 64) * Kd + k0 + c0e, lA + 2048 + e0);
        gload_lds16(Bb + (long)r0 * Kd + k0 + c0e, lB + e0);
        gload_lds16(Bb + (long)(r0 + 64) * Kd + k0 + c0e, lB + 2048 + e0);
        __syncthreads();

        short8 af[4], bf[4];
#pragma unroll
        for (int i = 0; i < 4; ++i)
            af[i] = *reinterpret_cast<const short8*>(lA + (wm * 64 + i * 16 + lane15) * 32 + lhi * 8);
#pragma unroll
        for (int j = 0; j < 4; ++j)
            bf[j] = *reinterpret_cast<const short8*>(lB + (wn * 64 + j * 16 + lane15) * 32 + lhi * 8);
#pragma unroll
        for (int i = 0; i < 4; ++i)
#pragma unroll
            for (int j = 0; j < 4; ++j)
                acc[i][j] = __builtin_amdgcn_mfma_f32_16x16x32_bf16(af[i], bf[j], acc[i][j], 0, 0, 0);
        __syncthreads();
    }

    // epilogue: D fragment (i,j): col = lane&15, row = (lane>>4)*4 + r
    long cOff = (long)b * cBatch;
    if (MODE == 0) {
        __hip_bfloat16* Cb = (__hip_bfloat16*)Cp + cOff;
#pragma unroll
        for (int i = 0; i < 4; ++i) {
            int gm = tm * 128 + wm * 64 + i * 16 + lhi * 4;
#pragma unroll
            for (int j = 0; j < 4; ++j) {
                int gn = tn * 128 + wn * 64 + j * 16 + lane15;
#pragma unroll
                for (int r = 0; r < 4; ++r)
                    Cb[(long)(gm + r) * N + gn] = __float2bfloat16(acc[i][j][r]);
            }
        }
    } else if (MODE == 1) {
        float* Cb = (float*)Cp + cOff;
#pragma unroll
        for (int i = 0; i < 4; ++i) {
            int gm = tm * 128 + wm * 64 + i * 16 + lhi * 4;
#pragma unroll
            for (int j = 0; j < 4; ++j) {
                int gn = tn * 128 + wn * 64 + j * 16 + lane15;
#pragma unroll
                for (int r = 0; r < 4; ++r)
                    Cb[(long)(gm + r) * N + gn] = acc[i][j][r] * scale;
            }
        }
    } else {
        float alpha = *alphaPtr;
        const float* Xb = X + (long)b * xBatch;
        float* Cb = (float*)Cp + cOff;
#pragma unroll
        for (int i = 0; i < 4; ++i) {
            int gm = tm * 128 + wm * 64 + i * 16 + lhi * 4;
#pragma unroll
            for (int j = 0; j < 4; ++j) {
                int gn = tn * 128 + wn * 64 + j * 16 + lane15;
#pragma unroll
                for (int r = 0; r < 4; ++r) {
                    long idx = (long)(gm + r) * N + gn;
                    Cb[idx] = alpha * acc[i][j][r] + Xb[idx];
                }
            }
        }
    }
}

extern "C" void kernel_launch(void* const* d_in, const int* in_sizes, int n_in,
                              void* d_out, int out_size, void* d_ws, size_t ws_size,
                              hipStream_t stream) {
    const float* x = (const float*)d_in[0];
    const float* Wk = (const float*)d_in[1];
    const float* Wq = (const float*)d_in[2];
    const float* Wv = (const float*)d_in[3];
    const float* Wr = (const float*)d_in[4];
    const float* alphaPtr = (const float*)d_in[5];

    char* ws = (char*)d_ws;
    size_t off = 0;
    auto alloc = [&](size_t bytes) {
        char* p = ws + off;
        off += (bytes + 255) & ~(size_t)255;
        return p;
    };
    const size_t BSC = (size_t)B_ * S_ * C_;
    __hip_bfloat16* xT = (__hip_bfloat16*)alloc(BSC * 2);
    __hip_bfloat16* Wkb = (__hip_bfloat16*)alloc((size_t)C_ * C_ * 2);
    __hip_bfloat16* Wqb = (__hip_bfloat16*)alloc((size_t)C_ * C_ * 2);
    __hip_bfloat16* Wvb = (__hip_bfloat16*)alloc((size_t)C_ * C_ * 2);
    __hip_bfloat16* Wrb = (__hip_bfloat16*)alloc((size_t)C_ * C_ * 2);
    __hip_bfloat16* K_T = (__hip_bfloat16*)alloc(BSC * 2);  // [B][S][C]
    __hip_bfloat16* Q_T = (__hip_bfloat16*)alloc(BSC * 2);  // [B][S][C]
    __hip_bfloat16* Vb = (__hip_bfloat16*)alloc(BSC * 2);   // [B][C][S]
    float* scores = (float*)alloc((size_t)B_ * S_ * S_ * 4);
    __hip_bfloat16* Abf = (__hip_bfloat16*)alloc((size_t)B_ * S_ * S_ * 2);
    __hip_bfloat16* attT = xT;  // reuse: xT dead after V projection

    const float scale = 1.0f / sqrtf((float)C_);
    const long SC = (long)S_ * C_;
    const long CS = (long)C_ * S_;
    const long SS = (long)S_ * S_;

    int nW = C_ * C_;
    cvt_f2b<<<(nW + 255) / 256, 256, 0, stream>>>(Wk, Wkb, nW);
    cvt_f2b<<<(nW + 255) / 256, 256, 0, stream>>>(Wq, Wqb, nW);
    cvt_f2b<<<(nW + 255) / 256, 256, 0, stream>>>(Wv, Wvb, nW);
    cvt_f2b<<<(nW + 255) / 256, 256, 0, stream>>>(Wr, Wrb, nW);

    transpose_cvt<<<dim3(S_ / 32, C_ / 32, B_), dim3(32, 8), 0, stream>>>(x, xT);

    // K_T[b][s][o] = sum_c xT[b][s][c] * Wk[o][c]   (M=S, N=C)
    gemm_tn<0><<<B_ * 2 * 10, 256, 0, stream>>>(xT, SC, Wkb, 0, K_T, SC,
                                                S_, C_, C_, 2, 10, 1.f, nullptr, nullptr, 0);
    gemm_tn<0><<<B_ * 2 * 10, 256, 0, stream>>>(xT, SC, Wqb, 0, Q_T, SC,
                                                S_, C_, C_, 2, 10, 1.f, nullptr, nullptr, 0);
    // V[b][o][s] = sum_c Wv[o][c] * xT[b][s][c]     (M=C, N=S)
    gemm_tn<0><<<B_ * 10 * 2, 256, 0, stream>>>(Wvb, 0, xT, SC, Vb, CS,
                                                C_, S_, C_, 10, 2, 1.f, nullptr, nullptr, 0);
    // scores[b][i][j] = scale * sum_c K_T[b][i][c]*Q_T[b][j][c]  (M=S, N=S) fp32
    gemm_tn<1><<<B_ * 2 * 2, 256, 0, stream>>>(K_T, SC, Q_T, SC, scores, SS,
                                               S_, S_, C_, 2, 2, scale, nullptr, nullptr, 0);
    // softmax over batch axis
    softmax_b<<<256, 256, 0, stream>>>(scores, Abf);
    // att_T[b][i][c] = sum_j Abf[b][i][j] * V[b][c][j]  (M=S, N=C, Kd=S)
    gemm_tn<0><<<B_ * 2 * 10, 256, 0, stream>>>(Abf, SS, Vb, CS, attT, SC,
                                                S_, C_, S_, 2, 10, 1.f, nullptr, nullptr, 0);
    // out[b][o][i] = alpha * sum_c Wr[o][c]*att_T[b][i][c] + x[b][o][i]  (M=C, N=S) fp32
    gemm_tn<2><<<B_ * 10 * 2, 256, 0, stream>>>(Wrb, 0, attT, SC, d_out, CS,
                                                C_, S_, C_, 10, 2, 1.f, alphaPtr, x, CS);
}

// Round 2
// 531.942 us; speedup vs baseline: 1.1868x; 1.1868x over previous
//
#include <hip/hip_runtime.h>
#include <hip/hip_bf16.h>
#include <cstdint>
#include <cmath>

#define B_ 64
#define C_ 1280
#define S_ 256

typedef __attribute__((ext_vector_type(8))) short short8;
typedef __attribute__((ext_vector_type(4))) float f32x4;

typedef const __attribute__((address_space(1))) char gch;
typedef __attribute__((address_space(3))) char lch;

__device__ __forceinline__ void gload_lds16(const void* g, void* l) {
    __builtin_amdgcn_global_load_lds((gch*)g, (lch*)l, 16, 0, 0);
}

// ---------------- weight fp32 -> bf16 ----------------
__global__ void cvt_f2b(const float* __restrict__ src, __hip_bfloat16* __restrict__ dst, int n) {
    int i = blockIdx.x * blockDim.x + threadIdx.x;
    if (i < n) dst[i] = __float2bfloat16(src[i]);
}

// ---------------- x [B][C][S] fp32 -> xT [B*S][C] bf16 ----------------
__global__ void transpose_cvt(const float* __restrict__ x, __hip_bfloat16* __restrict__ xT) {
    __shared__ float tile[32][33];
    int b = blockIdx.z;
    int s0 = blockIdx.x * 32, c0 = blockIdx.y * 32;
    int tx = threadIdx.x, ty = threadIdx.y;
    const float* xb = x + (long)b * C_ * S_;
#pragma unroll
    for (int dy = 0; dy < 32; dy += 8)
        tile[ty + dy][tx] = xb[(long)(c0 + ty + dy) * S_ + s0 + tx];
    __syncthreads();
    __hip_bfloat16* xTb = xT + (long)b * S_ * C_;
#pragma unroll
    for (int dy = 0; dy < 32; dy += 8)
        xTb[(long)(s0 + ty + dy) * C_ + c0 + tx] = __float2bfloat16(tile[tx][ty + dy]);
}

// ---------------- V slice of KQV [16384][3840] -> Vb [B][C][S] bf16 ----------------
__global__ void vtrans(const unsigned short* __restrict__ KQV, unsigned short* __restrict__ Vb) {
    __shared__ unsigned short tile[32][33];
    int b = blockIdx.z;
    int s0 = blockIdx.x * 32, c0 = blockIdx.y * 32;
    int tx = threadIdx.x, ty = threadIdx.y;
#pragma unroll
    for (int dy = 0; dy < 32; dy += 8)
        tile[ty + dy][tx] = KQV[(long)(b * 256 + s0 + ty + dy) * 3840 + 2560 + c0 + tx];
    __syncthreads();
#pragma unroll
    for (int dy = 0; dy < 32; dy += 8)
        Vb[(long)(b * 1280 + c0 + ty + dy) * 256 + s0 + tx] = tile[tx][ty + dy];
}

// ---------------- out[b][c][s] = alpha * R_T[(b*256+s)][c] + x[b][c][s] ----------------
__global__ void transadd(const __hip_bfloat16* __restrict__ R_T, const float* __restrict__ x,
                         const float* __restrict__ alphaPtr, float* __restrict__ out) {
    __shared__ float tile[32][33];
    float alpha = alphaPtr[0];
    int b = blockIdx.z;
    int s0 = blockIdx.x * 32, c0 = blockIdx.y * 32;
    int tx = threadIdx.x, ty = threadIdx.y;
#pragma unroll
    for (int dy = 0; dy < 32; dy += 8)
        tile[ty + dy][tx] = __bfloat162float(R_T[(long)(b * 256 + s0 + ty + dy) * 1280 + c0 + tx]);
    __syncthreads();
#pragma unroll
    for (int dy = 0; dy < 32; dy += 8) {
        long idx = (long)(b * 1280 + c0 + ty + dy) * 256 + s0 + tx;
        out[idx] = alpha * tile[tx][ty + dy] + x[idx];
    }
}

// ---------------- softmax over batch axis ----------------
__global__ void softmax_b(const float* __restrict__ scores, __hip_bfloat16* __restrict__ Abf) {
    int tid = blockIdx.x * blockDim.x + threadIdx.x;  // 0..65535
    float r[64];
    float mx = -1e30f;
#pragma unroll
    for (int b = 0; b < 64; ++b) {
        r[b] = scores[(long)b * 65536 + tid];
        mx = fmaxf(mx, r[b]);
    }
    float sum = 0.f;
#pragma unroll
    for (int b = 0; b < 64; ++b) {
        r[b] = __expf(r[b] - mx);
        sum += r[b];
    }
    float inv = 1.0f / sum;
#pragma unroll
    for (int b = 0; b < 64; ++b)
        Abf[(long)b * 65536 + tid] = __float2bfloat16(r[b] * inv);
}

// ================= 8-phase 256x256 TN GEMM (BK=64, 512 thr, 8 waves 2x4) =================
// C[m][n] = sum_k A[m][k]*B[n][k].  M = tiles*256 rows, N = tilesN*256, K multiple of 128.
// LDS: 8 slots x 16KB; slot(kt,j) = (kt&1)*4 + j;  j: 0=A rows[0,128) 1=A rows[128,256)
// 2=B rows[0,128) 3=B rows[128,256).  Half-tile layout (swizzled): byte(row,chunk) =
// row*128 + (chunk ^ (row&7))*16, chunk = k16B-chunk (8 per row of 64 bf16).
// Staging: linear LDS dest (t*16 / +8192), inverse-swizzled global source (rule 21).

#define PH_TOP()                                                \
    do {                                                        \
        __builtin_amdgcn_sched_barrier(0);                      \
        __builtin_amdgcn_s_barrier();                           \
        asm volatile("s_waitcnt lgkmcnt(0)" ::: "memory");      \
        __builtin_amdgcn_sched_barrier(0);                      \
        __builtin_amdgcn_s_setprio(1);                          \
    } while (0)

#define PH_BOT()                                                \
    do {                                                        \
        __builtin_amdgcn_s_setprio(0);                          \
        __builtin_amdgcn_sched_barrier(0);                      \
        __builtin_amdgcn_s_barrier();                           \
    } while (0)

#define PH_BOT_WAIT(LAST_)                                          \
    do {                                                            \
        __builtin_amdgcn_s_setprio(0);                              \
        __builtin_amdgcn_sched_barrier(0);                          \
        if (LAST_) asm volatile("s_waitcnt vmcnt(0)" ::: "memory"); \
        else       asm volatile("s_waitcnt vmcnt(2)" ::: "memory"); \
        __builtin_amdgcn_s_barrier();                               \
    } while (0)

#define MFMA_Q(MO, NO, BFV)                                                                        \
    _Pragma("unroll") for (int m = 0; m < 4; ++m) {                                                \
        _Pragma("unroll") for (int n = 0; n < 2; ++n) {                                            \
            acc[m + MO][n + NO] = __builtin_amdgcn_mfma_f32_16x16x32_bf16(                         \
                af[m][0], BFV[n][0], acc[m + MO][n + NO], 0, 0, 0);                                \
            acc[m + MO][n + NO] = __builtin_amdgcn_mfma_f32_16x16x32_bf16(                         \
                af[m][1], BFV[n][1], acc[m + MO][n + NO], 0, 0, 0);                                \
        }                                                                                          \
    }

#define LOAD_A(SLOT, RO)                                  \
    _Pragma("unroll") for (int m = 0; m < 4; ++m) {       \
        af[m][0] = RD(SLOT, (RO) + m * 16 + l15, 0);      \
        af[m][1] = RD(SLOT, (RO) + m * 16 + l15, 1);      \
    }

#define LOAD_B(SLOT, BFV, NO)                                    \
    _Pragma("unroll") for (int n = 0; n < 2; ++n) {              \
        BFV[n][0] = RD(SLOT, rB0 + ((NO) + n) * 16 + l15, 0);    \
        BFV[n][1] = RD(SLOT, rB0 + ((NO) + n) * 16 + l15, 1);    \
    }

__global__ __launch_bounds__(512, 2) void gemm8p(
    const __hip_bfloat16* __restrict__ A, const __hip_bfloat16* __restrict__ Bm,
    __hip_bfloat16* __restrict__ Cc,
    int lda, int ldb, int ldc, int Kd, int tilesN, int nwg) {
    __shared__ char lds[131072];

    int bid = blockIdx.x;
    int cpx = nwg >> 3;
    int swz = (bid & 7) * cpx + (bid >> 3);
    int tm = swz / tilesN, tn = swz - tm * tilesN;

    int t = threadIdx.x;
    int lane = t & 63, w = t >> 6;
    int wm = w >> 2, wn = w & 3;
    int l15 = lane & 15, lhi = lane >> 4;
    int rB0 = (wn & 1) * 64;
    const int sA0 = wm, sB0 = 2 + (wn >> 1);
    const int sA1 = 4 + wm, sB1 = 6 + (wn >> 1);

    const __hip_bfloat16* aT = A + (long)tm * 256 * lda;
    const __hip_bfloat16* bT = Bm + (long)tn * 256 * ldb;

    // staging precompute: thread t stages LDS bytes t*16 and t*16+8192 of a slot
    int srow = t >> 3;                      // 0..63
    int sc = ((t & 7) ^ (srow & 7)) * 8;    // inverse-swizzled k-chunk (elements)
    const __hip_bfloat16* stA = aT + (long)srow * lda + sc;
    const __hip_bfloat16* stB = bT + (long)srow * ldb + sc;

    auto STAGE = [&](int kt, int j) {
        const __hip_bfloat16* p;
        long ldg;
        if (j < 2) { p = stA + (long)j * 128 * lda + kt * 64; ldg = lda; }
        else       { p = stB + (long)(j - 2) * 128 * ldb + kt * 64; ldg = ldb; }
        char* slot = lds + (((kt & 1) * 4 + j) << 14);
        gload_lds16(p, slot + t * 16);
        gload_lds16(p + 64 * ldg, slot + t * 16 + 8192);
    };

    auto RD = [&](int slotIdx, int row, int kk) -> short8 {
        const char* p = lds + (slotIdx << 14) + row * 128 +
                        ((((kk << 2) + lhi) ^ (row & 7)) << 4);
        return *reinterpret_cast<const short8*>(p);
    };

    f32x4 acc[8][4];
#pragma unroll
    for (int i = 0; i < 8; ++i)
#pragma unroll
        for (int j = 0; j < 4; ++j) acc[i][j] = (f32x4){0.f, 0.f, 0.f, 0.f};

    short8 af[4][2], b0v[2][2], b1v[2][2];

    // ---- prologue: K-tile 0 (4 halves) + (1, j0); retire K-tile 0, carry 1 half ----
    STAGE(0, 0); STAGE(0, 1); STAGE(0, 2); STAGE(0, 3); STAGE(1, 0);
    asm volatile("s_waitcnt vmcnt(2)" ::: "memory");
    __builtin_amdgcn_s_barrier();
    __builtin_amdgcn_sched_barrier(0);

    const int NTH = Kd >> 7;  // iterations; 2 K-tiles each
    for (int i = 0; i < NTH; ++i) {
        const bool last = (i == NTH - 1);
        const int kt0 = 2 * i, kt1 = 2 * i + 1;

        // phase 0: kt0 q0 (m 0-3 x n 0-1)
        LOAD_A(sA0, 0)
        LOAD_B(sB0, b0v, 0)
        STAGE(kt1, 1);
        PH_TOP();
        MFMA_Q(0, 0, b0v)
        PH_BOT();

        // phase 1: kt0 q1 (m 0-3 x n 2-3)
        LOAD_B(sB0, b1v, 2)
        STAGE(kt1, 2);
        PH_TOP();
        MFMA_Q(0, 2, b1v)
        PH_BOT();

        // phase 2: kt0 q2 (m 4-7 x n 2-3)
        LOAD_A(sA0, 64)
        STAGE(kt1, 3);
        PH_TOP();
        MFMA_Q(4, 2, b1v)
        PH_BOT();

        // phase 3: kt0 q3 (m 4-7 x n 0-1); gate K-tile kt1
        if (!last) STAGE(kt0 + 2, 0);
        PH_TOP();
        MFMA_Q(4, 0, b0v)
        PH_BOT_WAIT(last);

        // phase 4: kt1 q0
        LOAD_A(sA1, 0)
        LOAD_B(sB1, b0v, 0)
        if (!last) STAGE(kt0 + 2, 1);
        PH_TOP();
        MFMA_Q(0, 0, b0v)
        PH_BOT();

        // phase 5: kt1 q1
        LOAD_B(sB1, b1v, 2)
        if (!last) STAGE(kt0 + 2, 2);
        PH_TOP();
        MFMA_Q(0, 2, b1v)
        PH_BOT();

        // phase 6: kt1 q2
        LOAD_A(sA1, 64)
        if (!last) STAGE(kt0 + 2, 3);
        PH_TOP();
        MFMA_Q(4, 2, b1v)
        PH_BOT();

        // phase 7: kt1 q3; gate K-tile kt0+2 (next iteration)
        if (!last) STAGE(kt0 + 3, 0);
        PH_TOP();
        MFMA_Q(4, 0, b0v)
        __builtin_amdgcn_s_setprio(0);
        __builtin_amdgcn_sched_barrier(0);
        if (!last) asm volatile("s_waitcnt vmcnt(2)" ::: "memory");
        __builtin_amdgcn_s_barrier();
    }

    // ---- epilogue: D frag (m,n): col = l15 (B-row), row = lhi*4 + r (A-row) ----
    long crow0 = (long)tm * 256 + wm * 128;
    int cc0 = tn * 256 + wn * 64;
#pragma unroll
    for (int m = 0; m < 8; ++m) {
        long gm = crow0 + m * 16 + lhi * 4;
#pragma unroll
        for (int n = 0; n < 4; ++n) {
            int gn = cc0 + n * 16 + l15;
#pragma unroll
            for (int r = 0; r < 4; ++r)
                Cc[(gm + r) * ldc + gn] = __float2bfloat16(acc[m][n][r]);
        }
    }
}

// ================= 128x128 TN GEMM (2-phase, 256 thr) for small batched GEMMs =================
// MODE 0: C bf16 = acc ; MODE 1: C fp32 = acc * scale
template <int MODE>
__global__ __launch_bounds__(256) void gemm_tn(
    const __hip_bfloat16* __restrict__ A, long aBatch, int lda,
    const __hip_bfloat16* __restrict__ Bm, long bBatch, int ldb,
    void* __restrict__ Cp, long cBatch, int ldc,
    int Kd, int tilesM, int tilesN, float scale) {
    __shared__ __hip_bfloat16 lA[128 * 32];
    __shared__ __hip_bfloat16 lB[128 * 32];

    int tiles = tilesM * tilesN;
    int blk = blockIdx.x;
    int b = blk / tiles;
    int rem = blk - b * tiles;
    int tm = rem / tilesN;
    int tn = rem - tm * tilesN;

    int t = threadIdx.x;
    int lane = t & 63;
    int w = t >> 6;
    int wm = w >> 1, wn = w & 1;
    int lane15 = lane & 15, lhi = lane >> 4;

    const __hip_bfloat16* Ab = A + (long)b * aBatch + (long)tm * 128 * lda;
    const __hip_bfloat16* Bb = Bm + (long)b * bBatch + (long)tn * 128 * ldb;

    f32x4 acc[4][4];
#pragma unroll
    for (int i = 0; i < 4; ++i)
#pragma unroll
        for (int j = 0; j < 4; ++j) acc[i][j] = (f32x4){0.f, 0.f, 0.f, 0.f};

    int e0 = t * 8;
    int r0 = e0 >> 5;
    int c0e = e0 & 31;

    for (int k0 = 0; k0 < Kd; k0 += 32) {
        gload_lds16(Ab + (long)r0 * lda + k0 + c0e, lA + e0);
        gload_lds16(Ab + (long)(r0 + 64) * lda + k0 + c0e, lA + 2048 + e0);
        gload_lds16(Bb + (long)r0 * ldb + k0 + c0e, lB + e0);
        gload_lds16(Bb + (long)(r0 + 64) * ldb + k0 + c0e, lB + 2048 + e0);
        __syncthreads();

        short8 af[4], bf[4];
#pragma unroll
        for (int i = 0; i < 4; ++i)
            af[i] = *reinterpret_cast<const short8*>(lA + (wm * 64 + i * 16 + lane15) * 32 + lhi * 8);
#pragma unroll
        for (int j = 0; j < 4; ++j)
            bf[j] = *reinterpret_cast<const short8*>(lB + (wn * 64 + j * 16 + lane15) * 32 + lhi * 8);
#pragma unroll
        for (int i = 0; i < 4; ++i)
#pragma unroll
            for (int j = 0; j < 4; ++j)
                acc[i][j] = __builtin_amdgcn_mfma_f32_16x16x32_bf16(af[i], bf[j], acc[i][j], 0, 0, 0);
        __syncthreads();
    }

    long cOff = (long)b * cBatch;
    if (MODE == 0) {
        __hip_bfloat16* Cb = (__hip_bfloat16*)Cp + cOff;
#pragma unroll
        for (int i = 0; i < 4; ++i) {
            int gm = tm * 128 + wm * 64 + i * 16 + lhi * 4;
#pragma unroll
            for (int j = 0; j < 4; ++j) {
                int gn = tn * 128 + wn * 64 + j * 16 + lane15;
#pragma unroll
                for (int r = 0; r < 4; ++r)
                    Cb[(long)(gm + r) * ldc + gn] = __float2bfloat16(acc[i][j][r]);
            }
        }
    } else {
        float* Cb = (float*)Cp + cOff;
#pragma unroll
        for (int i = 0; i < 4; ++i) {
            int gm = tm * 128 + wm * 64 + i * 16 + lhi * 4;
#pragma unroll
            for (int j = 0; j < 4; ++j) {
                int gn = tn * 128 + wn * 64 + j * 16 + lane15;
#pragma unroll
                for (int r = 0; r < 4; ++r)
                    Cb[(long)(gm + r) * ldc + gn] = acc[i][j][r] * scale;
            }
        }
    }
}

extern "C" void kernel_launch(void* const* d_in, const int* in_sizes, int n_in,
                              void* d_out, int out_size, void* d_ws, size_t ws_size,
                              hipStream_t stream) {
    const float* x = (const float*)d_in[0];
    const float* Wk = (const float*)d_in[1];
    const float* Wq = (const float*)d_in[2];
    const float* Wv = (const float*)d_in[3];
    const float* Wr = (const float*)d_in[4];
    const float* alphaPtr = (const float*)d_in[5];

    char* ws = (char*)d_ws;
    size_t off = 0;
    auto alloc = [&](size_t bytes) {
        char* p = ws + off;
        off += (bytes + 255) & ~(size_t)255;
        return p;
    };
    const size_t BSC = (size_t)B_ * S_ * C_;      // 16384*1280
    // xT region later reused for: scores (fp32, 16.8MB), then att_T (bf16, 42MB)
    char* xTregion = alloc(BSC * 2);
    __hip_bfloat16* xT = (__hip_bfloat16*)xTregion;
    __hip_bfloat16* Wcat = (__hip_bfloat16*)alloc((size_t)3 * C_ * C_ * 2);
    __hip_bfloat16* Wrb = (__hip_bfloat16*)alloc((size_t)C_ * C_ * 2);
    __hip_bfloat16* KQV = (__hip_bfloat16*)alloc((size_t)B_ * S_ * 3 * C_ * 2);  // [16384][3840]
    __hip_bfloat16* Abf = (__hip_bfloat16*)alloc((size_t)B_ * S_ * S_ * 2);
    __hip_bfloat16* Vb = (__hip_bfloat16*)alloc(BSC * 2);  // [B][C][S]

    float* scores = (float*)xTregion;                    // after xT dead
    __hip_bfloat16* att_T = (__hip_bfloat16*)xTregion;   // after scores dead
    __hip_bfloat16* R_T = KQV;                           // after KQV dead

    const float scale = 1.0f / sqrtf((float)C_);
    int nW = C_ * C_;

    // weights -> bf16 (Wk/Wq/Wv concatenated row-wise)
    cvt_f2b<<<(nW + 255) / 256, 256, 0, stream>>>(Wk, Wcat, nW);
    cvt_f2b<<<(nW + 255) / 256, 256, 0, stream>>>(Wq, Wcat + (size_t)C_ * C_, nW);
    cvt_f2b<<<(nW + 255) / 256, 256, 0, stream>>>(Wv, Wcat + (size_t)2 * C_ * C_, nW);
    cvt_f2b<<<(nW + 255) / 256, 256, 0, stream>>>(Wr, Wrb, nW);

    // x -> xT [16384][1280] bf16
    transpose_cvt<<<dim3(S_ / 32, C_ / 32, B_), dim3(32, 8), 0, stream>>>(x, xT);

    // KQV [16384][3840] = xT * Wcat^T   (8-phase 256^2)
    gemm8p<<<960, 512, 0, stream>>>(xT, Wcat, KQV, C_, C_, 3 * C_, C_, 15, 960);

    // V slice -> Vb [B][C][S]
    vtrans<<<dim3(8, 40, 64), dim3(32, 8), 0, stream>>>((const unsigned short*)KQV,
                                                        (unsigned short*)Vb);

    // scores[b][i][j] = scale * sum_c K_T[b,i,c]*Q_T[b,j,c]  (fp32, into xT region)
    gemm_tn<1><<<B_ * 4, 256, 0, stream>>>(KQV, (long)S_ * 3 * C_, 3 * C_,
                                           KQV + C_, (long)S_ * 3 * C_, 3 * C_,
                                           scores, (long)S_ * S_, S_,
                                           C_, 2, 2, scale);
    // softmax over batch axis
    softmax_b<<<256, 256, 0, stream>>>(scores, Abf);

    // att_T[b][i][c] = sum_j Abf[b,i,j] * Vb[b,c,j]  (bf16, into xT region)
    gemm_tn<0><<<B_ * 20, 256, 0, stream>>>(Abf, (long)S_ * S_, S_,
                                            Vb, (long)C_ * S_, S_,
                                            att_T, (long)S_ * C_, C_,
                                            S_, 2, 10, 1.f);

    // R_T [16384][1280] = att_T * Wr^T  (8-phase 256^2, into KQV region)
    gemm8p<<<320, 512, 0, stream>>>(att_T, Wrb, R_T, C_, C_, C_, C_, 5, 320);

    // out[b][c][s] = alpha * R_T[(b,s)][c] + x[b][c][s]
    transadd<<<dim3(8, 40, 64), dim3(32, 8), 0, stream>>>(R_T, x, alphaPtr, (float*)d_out);
}

// Round 3
// 503.197 us; speedup vs baseline: 1.2546x; 1.0571x over previous
//
#include <hip/hip_runtime.h>
#include <hip/hip_bf16.h>
#include <cstdint>
#include <cmath>

#define B_ 64
#define C_ 1280
#define S_ 256

typedef __attribute__((ext_vector_type(8))) short short8;
typedef __attribute__((ext_vector_type(4))) float f32x4;

typedef const __attribute__((address_space(1))) char gch;
typedef __attribute__((address_space(3))) char lch;

__device__ __forceinline__ void gload_lds16(const void* g, void* l) {
    __builtin_amdgcn_global_load_lds((gch*)g, (lch*)l, 16, 0, 0);
}

__device__ __forceinline__ unsigned short f2bu(float f) {
    __hip_bfloat16 h = __float2bfloat16(f);
    return *reinterpret_cast<unsigned short*>(&h);
}

// ---------------- all weights fp32 -> bf16 in one pass ----------------
__global__ void cvt_weights(const float* __restrict__ Wk, const float* __restrict__ Wq,
                            const float* __restrict__ Wv, const float* __restrict__ Wr,
                            __hip_bfloat16* __restrict__ Wcat, __hip_bfloat16* __restrict__ Wrb) {
    const int nW = C_ * C_;
    int i = blockIdx.x * blockDim.x + threadIdx.x;
    if (i >= 4 * nW) return;
    int seg = i / nW, off = i - seg * nW;
    float v;
    if (seg == 0) v = Wk[off];
    else if (seg == 1) v = Wq[off];
    else if (seg == 2) v = Wv[off];
    else v = Wr[off];
    if (seg < 3) Wcat[i] = __float2bfloat16(v);
    else Wrb[off] = __float2bfloat16(v);
}

// ---------------- x [B][C][S] fp32 -> xT [B*S][C] bf16 ----------------
__global__ void transpose_cvt(const float* __restrict__ x, __hip_bfloat16* __restrict__ xT) {
    __shared__ float tile[32][33];
    int b = blockIdx.z;
    int s0 = blockIdx.x * 32, c0 = blockIdx.y * 32;
    int tx = threadIdx.x, ty = threadIdx.y;
    const float* xb = x + (long)b * C_ * S_;
#pragma unroll
    for (int dy = 0; dy < 32; dy += 8)
        tile[ty + dy][tx] = xb[(long)(c0 + ty + dy) * S_ + s0 + tx];
    __syncthreads();
    __hip_bfloat16* xTb = xT + (long)b * S_ * C_;
#pragma unroll
    for (int dy = 0; dy < 32; dy += 8)
        xTb[(long)(s0 + ty + dy) * C_ + c0 + tx] = __float2bfloat16(tile[tx][ty + dy]);
}

// ---------------- softmax over batch axis ----------------
__global__ void softmax_b(const float* __restrict__ scores, __hip_bfloat16* __restrict__ Abf) {
    int tid = blockIdx.x * blockDim.x + threadIdx.x;  // 0..65535
    float r[64];
    float mx = -1e30f;
#pragma unroll
    for (int b = 0; b < 64; ++b) {
        r[b] = scores[(long)b * 65536 + tid];
        mx = fmaxf(mx, r[b]);
    }
    float sum = 0.f;
#pragma unroll
    for (int b = 0; b < 64; ++b) {
        r[b] = __expf(r[b] - mx);
        sum += r[b];
    }
    float inv = 1.0f / sum;
#pragma unroll
    for (int b = 0; b < 64; ++b)
        Abf[(long)b * 65536 + tid] = __float2bfloat16(r[b] * inv);
}

// ================= 8-phase 256x256 TN GEMM (BK=64, 512 thr, 8 waves 2x4) =================
// C[m][n] = sum_k A[m][k]*B[n][k].  M rows = (b*256+s) flattened; K multiple of 128.
// LDS: 8 slots x 16KB; slot(kt,j) = (kt&1)*4 + j;  j: 0=A rows[0,128) 1=A rows[128,256)
// 2=B rows[0,128) 3=B rows[128,256).  Swizzled half-tile: byte(row,chunk) =
// row*128 + (chunk ^ (row&7))*16.  Staging: linear LDS dest, inverse-swizzled global src.
// MODE 1 (KQV): tn < vTile -> bf16 row-major into Cc (ld ldc); tn >= vTile -> V written
//               transposed to Vb[b][c][s] bf16.
// MODE 2 (final): out[b][c][s] = alpha*acc + x[b][c][s], fp32, no Cc write.

#define PH_TOP()                                                \
    do {                                                        \
        __builtin_amdgcn_sched_barrier(0);                      \
        __builtin_amdgcn_s_barrier();                           \
        asm volatile("s_waitcnt lgkmcnt(0)" ::: "memory");      \
        __builtin_amdgcn_sched_barrier(0);                      \
        __builtin_amdgcn_s_setprio(1);                          \
    } while (0)

#define PH_BOT()                                                \
    do {                                                        \
        __builtin_amdgcn_s_setprio(0);                          \
        __builtin_amdgcn_sched_barrier(0);                      \
        __builtin_amdgcn_s_barrier();                           \
    } while (0)

#define PH_BOT_WAIT(LAST_)                                          \
    do {                                                            \
        __builtin_amdgcn_s_setprio(0);                              \
        __builtin_amdgcn_sched_barrier(0);                          \
        if (LAST_) asm volatile("s_waitcnt vmcnt(0)" ::: "memory"); \
        else       asm volatile("s_waitcnt vmcnt(2)" ::: "memory"); \
        __builtin_amdgcn_s_barrier();                               \
    } while (0)

#define MFMA_Q(MO, NO, BFV)                                                                        \
    _Pragma("unroll") for (int m = 0; m < 4; ++m) {                                                \
        _Pragma("unroll") for (int n = 0; n < 2; ++n) {                                            \
            acc[m + MO][n + NO] = __builtin_amdgcn_mfma_f32_16x16x32_bf16(                         \
                af[m][0], BFV[n][0], acc[m + MO][n + NO], 0, 0, 0);                                \
            acc[m + MO][n + NO] = __builtin_amdgcn_mfma_f32_16x16x32_bf16(                         \
                af[m][1], BFV[n][1], acc[m + MO][n + NO], 0, 0, 0);                                \
        }                                                                                          \
    }

#define LOAD_A(SLOT, RO)                                  \
    _Pragma("unroll") for (int m = 0; m < 4; ++m) {       \
        af[m][0] = RD(SLOT, (RO) + m * 16 + l15, 0);      \
        af[m][1] = RD(SLOT, (RO) + m * 16 + l15, 1);      \
    }

#define LOAD_B(SLOT, BFV, NO)                                    \
    _Pragma("unroll") for (int n = 0; n < 2; ++n) {              \
        BFV[n][0] = RD(SLOT, rB0 + ((NO) + n) * 16 + l15, 0);    \
        BFV[n][1] = RD(SLOT, rB0 + ((NO) + n) * 16 + l15, 1);    \
    }

template <int MODE>
__global__ __launch_bounds__(512, 2) void gemm8p(
    const __hip_bfloat16* __restrict__ A, const __hip_bfloat16* __restrict__ Bm,
    __hip_bfloat16* __restrict__ Cc, int lda, int ldb, int ldc,
    int Kd, int tilesN, int nwg, int vTile,
    __hip_bfloat16* __restrict__ Vb,
    const float* __restrict__ xF, const float* __restrict__ alphaPtr,
    float* __restrict__ outF) {
    __shared__ char lds[131072];

    int bid = blockIdx.x;
    int cpx = nwg >> 3;
    int swz = (bid & 7) * cpx + (bid >> 3);
    int tm = swz / tilesN, tn = swz - tm * tilesN;

    int t = threadIdx.x;
    int lane = t & 63, w = t >> 6;
    int wm = w >> 2, wn = w & 3;
    int l15 = lane & 15, lhi = lane >> 4;
    int rB0 = (wn & 1) * 64;
    const int sA0 = wm, sB0 = 2 + (wn >> 1);
    const int sA1 = 4 + wm, sB1 = 6 + (wn >> 1);

    const __hip_bfloat16* aT = A + (long)tm * 256 * lda;
    const __hip_bfloat16* bT = Bm + (long)tn * 256 * ldb;

    // staging: thread t stages LDS bytes t*16 and t*16+8192 of a slot
    int srow = t >> 3;                    // 0..63
    int sc = ((t & 7) ^ (srow & 7)) * 8;  // inverse-swizzled k-chunk (elements)
    const __hip_bfloat16* stA = aT + (long)srow * lda + sc;
    const __hip_bfloat16* stB = bT + (long)srow * ldb + sc;

    auto STAGE = [&](int kt, int j) {
        const __hip_bfloat16* p;
        long ldg;
        if (j < 2) { p = stA + (long)j * 128 * lda + kt * 64; ldg = lda; }
        else       { p = stB + (long)(j - 2) * 128 * ldb + kt * 64; ldg = ldb; }
        char* slot = lds + (((kt & 1) * 4 + j) << 14);
        gload_lds16(p, slot + t * 16);
        gload_lds16(p + 64 * ldg, slot + t * 16 + 8192);
    };

    auto RD = [&](int slotIdx, int row, int kk) -> short8 {
        const char* p = lds + (slotIdx << 14) + row * 128 +
                        ((((kk << 2) + lhi) ^ (row & 7)) << 4);
        return *reinterpret_cast<const short8*>(p);
    };

    f32x4 acc[8][4];
#pragma unroll
    for (int i = 0; i < 8; ++i)
#pragma unroll
        for (int j = 0; j < 4; ++j) acc[i][j] = (f32x4){0.f, 0.f, 0.f, 0.f};

    short8 af[4][2], b0v[2][2], b1v[2][2];

    // ---- prologue: K-tile 0 (4 halves) + (1, j0); retire K-tile 0, carry 1 half ----
    STAGE(0, 0); STAGE(0, 1); STAGE(0, 2); STAGE(0, 3); STAGE(1, 0);
    asm volatile("s_waitcnt vmcnt(2)" ::: "memory");
    __builtin_amdgcn_s_barrier();
    __builtin_amdgcn_sched_barrier(0);

    const int NTH = Kd >> 7;  // iterations; 2 K-tiles each
    for (int i = 0; i < NTH; ++i) {
        const bool last = (i == NTH - 1);
        const int kt0 = 2 * i, kt1 = 2 * i + 1;

        // phase 0: kt0 q0 (m 0-3 x n 0-1)
        LOAD_A(sA0, 0)
        LOAD_B(sB0, b0v, 0)
        STAGE(kt1, 1);
        PH_TOP();
        MFMA_Q(0, 0, b0v)
        PH_BOT();

        // phase 1: kt0 q1 (m 0-3 x n 2-3)
        LOAD_B(sB0, b1v, 2)
        STAGE(kt1, 2);
        PH_TOP();
        MFMA_Q(0, 2, b1v)
        PH_BOT();

        // phase 2: kt0 q2 (m 4-7 x n 2-3)
        LOAD_A(sA0, 64)
        STAGE(kt1, 3);
        PH_TOP();
        MFMA_Q(4, 2, b1v)
        PH_BOT();

        // phase 3: kt0 q3 (m 4-7 x n 0-1); gate K-tile kt1
        if (!last) STAGE(kt0 + 2, 0);
        PH_TOP();
        MFMA_Q(4, 0, b0v)
        PH_BOT_WAIT(last);

        // phase 4: kt1 q0
        LOAD_A(sA1, 0)
        LOAD_B(sB1, b0v, 0)
        if (!last) STAGE(kt0 + 2, 1);
        PH_TOP();
        MFMA_Q(0, 0, b0v)
        PH_BOT();

        // phase 5: kt1 q1
        LOAD_B(sB1, b1v, 2)
        if (!last) STAGE(kt0 + 2, 2);
        PH_TOP();
        MFMA_Q(0, 2, b1v)
        PH_BOT();

        // phase 6: kt1 q2
        LOAD_A(sA1, 64)
        if (!last) STAGE(kt0 + 2, 3);
        PH_TOP();
        MFMA_Q(4, 2, b1v)
        PH_BOT();

        // phase 7: kt1 q3; gate K-tile kt0+2 (next iteration)
        if (!last) STAGE(kt0 + 3, 0);
        PH_TOP();
        MFMA_Q(4, 0, b0v)
        __builtin_amdgcn_s_setprio(0);
        __builtin_amdgcn_sched_barrier(0);
        if (!last) asm volatile("s_waitcnt vmcnt(2)" ::: "memory");
        __builtin_amdgcn_s_barrier();
    }

    // ---- epilogue: D frag (m,n): col = l15 (B-row), row = lhi*4 + r (A-row) ----
    if constexpr (MODE == 1) {
        if (tn < vTile) {
            long crow0 = (long)tm * 256 + wm * 128;
            int cc0 = tn * 256 + wn * 64;
#pragma unroll
            for (int m = 0; m < 8; ++m) {
                long gm = crow0 + m * 16 + lhi * 4;
#pragma unroll
                for (int n = 0; n < 4; ++n) {
                    int gn = cc0 + n * 16 + l15;
#pragma unroll
                    for (int r = 0; r < 4; ++r)
                        Cc[(gm + r) * ldc + gn] = __float2bfloat16(acc[m][n][r]);
                }
            }
        } else {
            // V region: write transposed to Vb[b][c][s], b = tm
            unsigned short* Vus = (unsigned short*)Vb;
            int cb0 = (tn - vTile) * 256 + wn * 64;
#pragma unroll
            for (int m = 0; m < 8; ++m) {
                int s0 = wm * 128 + m * 16 + lhi * 4;
#pragma unroll
                for (int n = 0; n < 4; ++n) {
                    int c = cb0 + n * 16 + l15;
                    ushort4 pk;
                    pk.x = f2bu(acc[m][n][0]);
                    pk.y = f2bu(acc[m][n][1]);
                    pk.z = f2bu(acc[m][n][2]);
                    pk.w = f2bu(acc[m][n][3]);
                    *reinterpret_cast<ushort4*>(&Vus[((long)(tm * 1280 + c) << 8) + s0]) = pk;
                }
            }
        }
    } else {
        // MODE 2: out[b][c][s] = alpha*acc + x[b][c][s], b = tm, s from row
        float alpha = alphaPtr[0];
#pragma unroll
        for (int m = 0; m < 8; ++m) {
            int s0 = wm * 128 + m * 16 + lhi * 4;
#pragma unroll
            for (int n = 0; n < 4; ++n) {
                int c = tn * 256 + wn * 64 + n * 16 + l15;
                long base = ((long)(tm * 1280 + c) << 8) + s0;
                f32x4 xv = *reinterpret_cast<const f32x4*>(xF + base);
                f32x4 o;
#pragma unroll
                for (int r = 0; r < 4; ++r) o[r] = alpha * acc[m][n][r] + xv[r];
                *reinterpret_cast<f32x4*>(outF + base) = o;
            }
        }
    }
}

// ================= 128x128 TN GEMM (2-phase, 256 thr) for small batched GEMMs =================
// MODE 0: C bf16 = acc ; MODE 1: C fp32 = acc * scale
template <int MODE>
__global__ __launch_bounds__(256) void gemm_tn(
    const __hip_bfloat16* __restrict__ A, long aBatch, int lda,
    const __hip_bfloat16* __restrict__ Bm, long bBatch, int ldb,
    void* __restrict__ Cp, long cBatch, int ldc,
    int Kd, int tilesM, int tilesN, float scale) {
    __shared__ __hip_bfloat16 lA[128 * 32];
    __shared__ __hip_bfloat16 lB[128 * 32];

    int tiles = tilesM * tilesN;
    int blk = blockIdx.x;
    int b = blk / tiles;
    int rem = blk - b * tiles;
    int tm = rem / tilesN;
    int tn = rem - tm * tilesN;

    int t = threadIdx.x;
    int lane = t & 63;
    int w = t >> 6;
    int wm = w >> 1, wn = w & 1;
    int lane15 = lane & 15, lhi = lane >> 4;

    const __hip_bfloat16* Ab = A + (long)b * aBatch + (long)tm * 128 * lda;
    const __hip_bfloat16* Bb = Bm + (long)b * bBatch + (long)tn * 128 * ldb;

    f32x4 acc[4][4];
#pragma unroll
    for (int i = 0; i < 4; ++i)
#pragma unroll
        for (int j = 0; j < 4; ++j) acc[i][j] = (f32x4){0.f, 0.f, 0.f, 0.f};

    int e0 = t * 8;
    int r0 = e0 >> 5;
    int c0e = e0 & 31;

    for (int k0 = 0; k0 < Kd; k0 += 32) {
        gload_lds16(Ab + (long)r0 * lda + k0 + c0e, lA + e0);
        gload_lds16(Ab + (long)(r0 + 64) * lda + k0 + c0e, lA + 2048 + e0);
        gload_lds16(Bb + (long)r0 * ldb + k0 + c0e, lB + e0);
        gload_lds16(Bb + (long)(r0 + 64) * ldb + k0 + c0e, lB + 2048 + e0);
        __syncthreads();

        short8 af[4], bf[4];
#pragma unroll
        for (int i = 0; i < 4; ++i)
            af[i] = *reinterpret_cast<const short8*>(lA + (wm * 64 + i * 16 + lane15) * 32 + lhi * 8);
#pragma unroll
        for (int j = 0; j < 4; ++j)
            bf[j] = *reinterpret_cast<const short8*>(lB + (wn * 64 + j * 16 + lane15) * 32 + lhi * 8);
#pragma unroll
        for (int i = 0; i < 4; ++i)
#pragma unroll
            for (int j = 0; j < 4; ++j)
                acc[i][j] = __builtin_amdgcn_mfma_f32_16x16x32_bf16(af[i], bf[j], acc[i][j], 0, 0, 0);
        __syncthreads();
    }

    long cOff = (long)b * cBatch;
    if (MODE == 0) {
        __hip_bfloat16* Cb = (__hip_bfloat16*)Cp + cOff;
#pragma unroll
        for (int i = 0; i < 4; ++i) {
            int gm = tm * 128 + wm * 64 + i * 16 + lhi * 4;
#pragma unroll
            for (int j = 0; j < 4; ++j) {
                int gn = tn * 128 + wn * 64 + j * 16 + lane15;
#pragma unroll
                for (int r = 0; r < 4; ++r)
                    Cb[(long)(gm + r) * ldc + gn] = __float2bfloat16(acc[i][j][r]);
            }
        }
    } else {
        float* Cb = (float*)Cp + cOff;
#pragma unroll
        for (int i = 0; i < 4; ++i) {
            int gm = tm * 128 + wm * 64 + i * 16 + lhi * 4;
#pragma unroll
            for (int j = 0; j < 4; ++j) {
                int gn = tn * 128 + wn * 64 + j * 16 + lane15;
#pragma unroll
                for (int r = 0; r < 4; ++r)
                    Cb[(long)(gm + r) * ldc + gn] = acc[i][j][r] * scale;
            }
        }
    }
}

extern "C" void kernel_launch(void* const* d_in, const int* in_sizes, int n_in,
                              void* d_out, int out_size, void* d_ws, size_t ws_size,
                              hipStream_t stream) {
    const float* x = (const float*)d_in[0];
    const float* Wk = (const float*)d_in[1];
    const float* Wq = (const float*)d_in[2];
    const float* Wv = (const float*)d_in[3];
    const float* Wr = (const float*)d_in[4];
    const float* alphaPtr = (const float*)d_in[5];

    char* ws = (char*)d_ws;
    size_t off = 0;
    auto alloc = [&](size_t bytes) {
        char* p = ws + off;
        off += (bytes + 255) & ~(size_t)255;
        return p;
    };
    const size_t BSC = (size_t)B_ * S_ * C_;  // 16384*1280
    // xT region reused for: scores (fp32, 16.8MB), then att_T (bf16, 42MB)
    char* xTregion = alloc(BSC * 2);
    __hip_bfloat16* xT = (__hip_bfloat16*)xTregion;
    __hip_bfloat16* Wcat = (__hip_bfloat16*)alloc((size_t)3 * C_ * C_ * 2);
    __hip_bfloat16* Wrb = (__hip_bfloat16*)alloc((size_t)C_ * C_ * 2);
    __hip_bfloat16* KQ = (__hip_bfloat16*)alloc((size_t)B_ * S_ * 2 * C_ * 2);  // [16384][2560]
    __hip_bfloat16* Abf = (__hip_bfloat16*)alloc((size_t)B_ * S_ * S_ * 2);
    __hip_bfloat16* Vb = (__hip_bfloat16*)alloc(BSC * 2);  // [B][C][S]

    float* scores = (float*)xTregion;                   // after xT dead
    __hip_bfloat16* att_T = (__hip_bfloat16*)xTregion;  // after scores dead

    const float scale = 1.0f / sqrtf((float)C_);
    int nW = C_ * C_;

    // weights -> bf16 (Wk/Wq/Wv concatenated row-wise) — one launch
    cvt_weights<<<(4 * nW + 255) / 256, 256, 0, stream>>>(Wk, Wq, Wv, Wr, Wcat, Wrb);

    // x -> xT [16384][1280] bf16
    transpose_cvt<<<dim3(S_ / 32, C_ / 32, B_), dim3(32, 8), 0, stream>>>(x, xT);

    // KQV: K/Q -> KQ [16384][2560]; V -> Vb [B][C][S] (fused transpose epilogue)
    gemm8p<1><<<960, 512, 0, stream>>>(xT, Wcat, KQ, C_, C_, 2 * C_,
                                       C_, 15, 960, 10, Vb, nullptr, nullptr, nullptr);

    // scores[b][i][j] = scale * sum_c K[b,i,c]*Q[b,j,c]  (fp32, into xT region)
    gemm_tn<1><<<B_ * 4, 256, 0, stream>>>(KQ, (long)S_ * 2 * C_, 2 * C_,
                                           KQ + C_, (long)S_ * 2 * C_, 2 * C_,
                                           scores, (long)S_ * S_, S_,
                                           C_, 2, 2, scale);
    // softmax over batch axis
    softmax_b<<<256, 256, 0, stream>>>(scores, Abf);

    // att_T[b][i][c] = sum_j Abf[b,i,j] * Vb[b,c,j]  (bf16, into xT region)
    gemm_tn<0><<<B_ * 20, 256, 0, stream>>>(Abf, (long)S_ * S_, S_,
                                            Vb, (long)C_ * S_, S_,
                                            att_T, (long)S_ * C_, C_,
                                            S_, 2, 10, 1.f);

    // out[b][c][s] = alpha * (att_T * Wr^T)[(b,s)][c] + x[b][c][s]  (fused epilogue)
    gemm8p<2><<<320, 512, 0, stream>>>(att_T, Wrb, nullptr, C_, C_, 0,
                                       C_, 5, 320, 0, nullptr, x, alphaPtr, (float*)d_out);
}

// Round 5
// 431.601 us; speedup vs baseline: 1.4627x; 1.1659x over previous
//
#include <hip/hip_runtime.h>
#include <hip/hip_bf16.h>
#include <cstdint>
#include <cmath>

#define B_ 64
#define C_ 1280
#define S_ 256

typedef __attribute__((ext_vector_type(8))) short short8;
typedef __attribute__((ext_vector_type(4))) float f32x4;

typedef const __attribute__((address_space(1))) char gch;
typedef __attribute__((address_space(3))) char lch;

__device__ __forceinline__ void gload_lds16(const void* g, void* l) {
    __builtin_amdgcn_global_load_lds((gch*)g, (lch*)l, 16, 0, 0);
}

__device__ __forceinline__ unsigned short f2bu(float f) {
    __hip_bfloat16 h = __float2bfloat16(f);
    return *reinterpret_cast<unsigned short*>(&h);
}

// ---------------- weights: transpose-convert to bf16 ----------------
// z=0: WqT[c][o] <- Wq[o][c]; z=1: WkT <- Wk; z=2: WvT <- Wv; z=3: Wrb (plain copy)
__global__ void prep_weights(const float* __restrict__ Wk, const float* __restrict__ Wq,
                             const float* __restrict__ Wv, const float* __restrict__ Wr,
                             __hip_bfloat16* __restrict__ WqT, __hip_bfloat16* __restrict__ WkT,
                             __hip_bfloat16* __restrict__ WvT, __hip_bfloat16* __restrict__ Wrb) {
    __shared__ float tile[32][33];
    int z = blockIdx.z;
    const float* src = (z == 0) ? Wq : (z == 1) ? Wk : (z == 2) ? Wv : Wr;
    __hip_bfloat16* dst = (z == 0) ? WqT : (z == 1) ? WkT : (z == 2) ? WvT : Wrb;
    int r0 = blockIdx.x * 32, c0 = blockIdx.y * 32;
    int tx = threadIdx.x, ty = threadIdx.y;
    if (z == 3) {
#pragma unroll
        for (int dy = 0; dy < 32; dy += 8) {
            int idx = (r0 + ty + dy) * C_ + c0 + tx;
            dst[idx] = __float2bfloat16(src[idx]);
        }
        return;
    }
#pragma unroll
    for (int dy = 0; dy < 32; dy += 8)
        tile[ty + dy][tx] = src[(long)(r0 + ty + dy) * C_ + c0 + tx];
    __syncthreads();
#pragma unroll
    for (int dy = 0; dy < 32; dy += 8)
        dst[(long)(c0 + ty + dy) * C_ + r0 + tx] = __float2bfloat16(tile[tx][ty + dy]);
}

// ---------------- x [B][C][S] fp32 -> xT [B*S][C] bf16 ----------------
__global__ void transpose_cvt(const float* __restrict__ x, __hip_bfloat16* __restrict__ xT) {
    __shared__ float tile[32][33];
    int b = blockIdx.z;
    int s0 = blockIdx.x * 32, c0 = blockIdx.y * 32;
    int tx = threadIdx.x, ty = threadIdx.y;
    const float* xb = x + (long)b * C_ * S_;
#pragma unroll
    for (int dy = 0; dy < 32; dy += 8)
        tile[ty + dy][tx] = xb[(long)(c0 + ty + dy) * S_ + s0 + tx];
    __syncthreads();
    __hip_bfloat16* xTb = xT + (long)b * S_ * C_;
#pragma unroll
    for (int dy = 0; dy < 32; dy += 8)
        xTb[(long)(s0 + ty + dy) * C_ + c0 + tx] = __float2bfloat16(tile[tx][ty + dy]);
}

// ---------------- softmax over batch axis ----------------
__global__ void softmax_b(const float* __restrict__ scores, __hip_bfloat16* __restrict__ Abf) {
    int tid = blockIdx.x * blockDim.x + threadIdx.x;  // 0..65535
    float r[64];
    float mx = -1e30f;
#pragma unroll
    for (int b = 0; b < 64; ++b) {
        r[b] = scores[(long)b * 65536 + tid];
        mx = fmaxf(mx, r[b]);
    }
    float sum = 0.f;
#pragma unroll
    for (int b = 0; b < 64; ++b) {
        r[b] = __expf(r[b] - mx);
        sum += r[b];
    }
    float inv = 1.0f / sum;
#pragma unroll
    for (int b = 0; b < 64; ++b)
        Abf[(long)b * 65536 + tid] = __float2bfloat16(r[b] * inv);
}

// ================= 8-phase 256x256 TN GEMM (BK=64, 512 thr, 8 waves 2x4) =================
// C[m][n] = sum_k A[m][k]*B[n][k].  tn < vTile -> bf16 row-major into Cc;
// tn >= vTile -> output written transposed to Vb[b(tm)][c][s] bf16 (the P projection).

#define PH_TOP()                                                \
    do {                                                        \
        __builtin_amdgcn_sched_barrier(0);                      \
        __builtin_amdgcn_s_barrier();                           \
        asm volatile("s_waitcnt lgkmcnt(0)" ::: "memory");      \
        __builtin_amdgcn_sched_barrier(0);                      \
        __builtin_amdgcn_s_setprio(1);                          \
    } while (0)

#define PH_BOT()                                                \
    do {                                                        \
        __builtin_amdgcn_s_setprio(0);                          \
        __builtin_amdgcn_sched_barrier(0);                      \
        __builtin_amdgcn_s_barrier();                           \
    } while (0)

#define PH_BOT_WAIT(LAST_)                                          \
    do {                                                            \
        __builtin_amdgcn_s_setprio(0);                              \
        __builtin_amdgcn_sched_barrier(0);                          \
        if (LAST_) asm volatile("s_waitcnt vmcnt(0)" ::: "memory"); \
        else       asm volatile("s_waitcnt vmcnt(2)" ::: "memory"); \
        __builtin_amdgcn_s_barrier();                               \
    } while (0)

#define MFMA_Q(MO, NO, BFV)                                                                        \
    _Pragma("unroll") for (int m = 0; m < 4; ++m) {                                                \
        _Pragma("unroll") for (int n = 0; n < 2; ++n) {                                            \
            acc[m + MO][n + NO] = __builtin_amdgcn_mfma_f32_16x16x32_bf16(                         \
                af[m][0], BFV[n][0], acc[m + MO][n + NO], 0, 0, 0);                                \
            acc[m + MO][n + NO] = __builtin_amdgcn_mfma_f32_16x16x32_bf16(                         \
                af[m][1], BFV[n][1], acc[m + MO][n + NO], 0, 0, 0);                                \
        }                                                                                          \
    }

#define LOAD_A(SLOT, RO)                                  \
    _Pragma("unroll") for (int m = 0; m < 4; ++m) {       \
        af[m][0] = RD(SLOT, (RO) + m * 16 + l15, 0);      \
        af[m][1] = RD(SLOT, (RO) + m * 16 + l15, 1);      \
    }

#define LOAD_B(SLOT, BFV, NO)                                    \
    _Pragma("unroll") for (int n = 0; n < 2; ++n) {              \
        BFV[n][0] = RD(SLOT, rB0 + ((NO) + n) * 16 + l15, 0);    \
        BFV[n][1] = RD(SLOT, rB0 + ((NO) + n) * 16 + l15, 1);    \
    }

__global__ __launch_bounds__(512, 2) void gemm8p(
    const __hip_bfloat16* __restrict__ A, const __hip_bfloat16* __restrict__ Bm,
    __hip_bfloat16* __restrict__ Cc, int lda, int ldb, int ldc,
    int Kd, int tilesN, int nwg, int vTile,
    __hip_bfloat16* __restrict__ Vb) {
    __shared__ char lds[131072];

    int bid = blockIdx.x;
    int cpx = nwg >> 3;
    int swz = (bid & 7) * cpx + (bid >> 3);
    int tm = swz / tilesN, tn = swz - tm * tilesN;

    int t = threadIdx.x;
    int lane = t & 63, w = t >> 6;
    int wm = w >> 2, wn = w & 3;
    int l15 = lane & 15, lhi = lane >> 4;
    int rB0 = (wn & 1) * 64;
    const int sA0 = wm, sB0 = 2 + (wn >> 1);
    const int sA1 = 4 + wm, sB1 = 6 + (wn >> 1);

    const __hip_bfloat16* aT = A + (long)tm * 256 * lda;
    const __hip_bfloat16* bT = Bm + (long)tn * 256 * ldb;

    int srow = t >> 3;
    int sc = ((t & 7) ^ (srow & 7)) * 8;
    const __hip_bfloat16* stA = aT + (long)srow * lda + sc;
    const __hip_bfloat16* stB = bT + (long)srow * ldb + sc;

    auto STAGE = [&](int kt, int j) {
        const __hip_bfloat16* p;
        long ldg;
        if (j < 2) { p = stA + (long)j * 128 * lda + kt * 64; ldg = lda; }
        else       { p = stB + (long)(j - 2) * 128 * ldb + kt * 64; ldg = ldb; }
        char* slot = lds + (((kt & 1) * 4 + j) << 14);
        gload_lds16(p, slot + t * 16);
        gload_lds16(p + 64 * ldg, slot + t * 16 + 8192);
    };

    auto RD = [&](int slotIdx, int row, int kk) -> short8 {
        const char* p = lds + (slotIdx << 14) + row * 128 +
                        ((((kk << 2) + lhi) ^ (row & 7)) << 4);
        return *reinterpret_cast<const short8*>(p);
    };

    f32x4 acc[8][4];
#pragma unroll
    for (int i = 0; i < 8; ++i)
#pragma unroll
        for (int j = 0; j < 4; ++j) acc[i][j] = (f32x4){0.f, 0.f, 0.f, 0.f};

    short8 af[4][2], b0v[2][2], b1v[2][2];

    STAGE(0, 0); STAGE(0, 1); STAGE(0, 2); STAGE(0, 3); STAGE(1, 0);
    asm volatile("s_waitcnt vmcnt(2)" ::: "memory");
    __builtin_amdgcn_s_barrier();
    __builtin_amdgcn_sched_barrier(0);

    const int NTH = Kd >> 7;
    for (int i = 0; i < NTH; ++i) {
        const bool last = (i == NTH - 1);
        const int kt0 = 2 * i, kt1 = 2 * i + 1;

        LOAD_A(sA0, 0)
        LOAD_B(sB0, b0v, 0)
        STAGE(kt1, 1);
        PH_TOP();
        MFMA_Q(0, 0, b0v)
        PH_BOT();

        LOAD_B(sB0, b1v, 2)
        STAGE(kt1, 2);
        PH_TOP();
        MFMA_Q(0, 2, b1v)
        PH_BOT();

        LOAD_A(sA0, 64)
        STAGE(kt1, 3);
        PH_TOP();
        MFMA_Q(4, 2, b1v)
        PH_BOT();

        if (!last) STAGE(kt0 + 2, 0);
        PH_TOP();
        MFMA_Q(4, 0, b0v)
        PH_BOT_WAIT(last);

        LOAD_A(sA1, 0)
        LOAD_B(sB1, b0v, 0)
        if (!last) STAGE(kt0 + 2, 1);
        PH_TOP();
        MFMA_Q(0, 0, b0v)
        PH_BOT();

        LOAD_B(sB1, b1v, 2)
        if (!last) STAGE(kt0 + 2, 2);
        PH_TOP();
        MFMA_Q(0, 2, b1v)
        PH_BOT();

        LOAD_A(sA1, 64)
        if (!last) STAGE(kt0 + 2, 3);
        PH_TOP();
        MFMA_Q(4, 2, b1v)
        PH_BOT();

        if (!last) STAGE(kt0 + 3, 0);
        PH_TOP();
        MFMA_Q(4, 0, b0v)
        __builtin_amdgcn_s_setprio(0);
        __builtin_amdgcn_sched_barrier(0);
        if (!last) asm volatile("s_waitcnt vmcnt(2)" ::: "memory");
        __builtin_amdgcn_s_barrier();
    }

    // epilogue: D frag (m,n): col = l15 (B-row), row = lhi*4 + r (A-row)
    if (tn < vTile) {
        long crow0 = (long)tm * 256 + wm * 128;
        int cc0 = tn * 256 + wn * 64;
#pragma unroll
        for (int m = 0; m < 8; ++m) {
            long gm = crow0 + m * 16 + lhi * 4;
#pragma unroll
            for (int n = 0; n < 4; ++n) {
                int gn = cc0 + n * 16 + l15;
#pragma unroll
                for (int r = 0; r < 4; ++r)
                    Cc[(gm + r) * ldc + gn] = __float2bfloat16(acc[m][n][r]);
            }
        }
    } else {
        // P region: write transposed to Vb[b][c][s], b = tm
        unsigned short* Vus = (unsigned short*)Vb;
        int cb0 = (tn - vTile) * 256 + wn * 64;
#pragma unroll
        for (int m = 0; m < 8; ++m) {
            int s0 = wm * 128 + m * 16 + lhi * 4;
#pragma unroll
            for (int n = 0; n < 4; ++n) {
                int c = cb0 + n * 16 + l15;
                ushort4 pk;
                pk.x = f2bu(acc[m][n][0]);
                pk.y = f2bu(acc[m][n][1]);
                pk.z = f2bu(acc[m][n][2]);
                pk.w = f2bu(acc[m][n][3]);
                *reinterpret_cast<ushort4*>(&Vus[((long)(tm * 1280 + c) << 8) + s0]) = pk;
            }
        }
    }
}

// ================= 128x128 TN GEMM (2-phase, 256 thr) =================
// MODE 1: C fp32 = acc * scale (batched)
template <int MODE>
__global__ __launch_bounds__(256) void gemm_tn(
    const __hip_bfloat16* __restrict__ A, long aBatch, int lda,
    const __hip_bfloat16* __restrict__ Bm, long bBatch, int ldb,
    void* __restrict__ Cp, long cBatch, int ldc,
    int Kd, int tilesM, int tilesN, float scale) {
    __shared__ __hip_bfloat16 lA[128 * 32];
    __shared__ __hip_bfloat16 lB[128 * 32];

    int tiles = tilesM * tilesN;
    int blk = blockIdx.x;
    int b = blk / tiles;
    int rem = blk - b * tiles;
    int tm = rem / tilesN;
    int tn = rem - tm * tilesN;

    int t = threadIdx.x;
    int lane = t & 63;
    int w = t >> 6;
    int wm = w >> 1, wn = w & 1;
    int lane15 = lane & 15, lhi = lane >> 4;

    const __hip_bfloat16* Ab = A + (long)b * aBatch + (long)tm * 128 * lda;
    const __hip_bfloat16* Bb = Bm + (long)b * bBatch + (long)tn * 128 * ldb;

    f32x4 acc[4][4];
#pragma unroll
    for (int i = 0; i < 4; ++i)
#pragma unroll
        for (int j = 0; j < 4; ++j) acc[i][j] = (f32x4){0.f, 0.f, 0.f, 0.f};

    int e0 = t * 8;
    int r0 = e0 >> 5;
    int c0e = e0 & 31;

    for (int k0 = 0; k0 < Kd; k0 += 32) {
        gload_lds16(Ab + (long)r0 * lda + k0 + c0e, lA + e0);
        gload_lds16(Ab + (long)(r0 + 64) * lda + k0 + c0e, lA + 2048 + e0);
        gload_lds16(Bb + (long)r0 * ldb + k0 + c0e, lB + e0);
        gload_lds16(Bb + (long)(r0 + 64) * ldb + k0 + c0e, lB + 2048 + e0);
        __syncthreads();

        short8 af[4], bf[4];
#pragma unroll
        for (int i = 0; i < 4; ++i)
            af[i] = *reinterpret_cast<const short8*>(lA + (wm * 64 + i * 16 + lane15) * 32 + lhi * 8);
#pragma unroll
        for (int j = 0; j < 4; ++j)
            bf[j] = *reinterpret_cast<const short8*>(lB + (wn * 64 + j * 16 + lane15) * 32 + lhi * 8);
#pragma unroll
        for (int i = 0; i < 4; ++i)
#pragma unroll
            for (int j = 0; j < 4; ++j)
                acc[i][j] = __builtin_amdgcn_mfma_f32_16x16x32_bf16(af[i], bf[j], acc[i][j], 0, 0, 0);
        __syncthreads();
    }

    long cOff = (long)b * cBatch;
    float* Cb = (float*)Cp + cOff;
#pragma unroll
    for (int i = 0; i < 4; ++i) {
        int gm = tm * 128 + wm * 64 + i * 16 + lhi * 4;
#pragma unroll
        for (int j = 0; j < 4; ++j) {
            int gn = tn * 128 + wn * 64 + j * 16 + lane15;
#pragma unroll
            for (int r = 0; r < 4; ++r)
                Cb[(long)(gm + r) * ldc + gn] = acc[i][j][r] * scale;
        }
    }
}

// ====== gemm_weights: two 1280x1280x1280 TN GEMMs in one dispatch (200 blocks) ======
// blk<100: Bcat[0..1280) = scale * WqT x WkT   (Bproj[c'][c] = scale*sum_o Wq[o][c']Wk[o][c])
// blk>=100: Bcat[1280..2560) = Wrb x WvT       (Wrv[o][c] = sum_m Wr[o][m]Wv[m][c])
__global__ __launch_bounds__(256) void gemm_weights(
    const __hip_bfloat16* __restrict__ WqT, const __hip_bfloat16* __restrict__ WkT,
    const __hip_bfloat16* __restrict__ Wrb, const __hip_bfloat16* __restrict__ WvT,
    __hip_bfloat16* __restrict__ Bcat, float scale) {
    __shared__ __hip_bfloat16 lA[128 * 32];
    __shared__ __hip_bfloat16 lB[128 * 32];

    int blk = blockIdx.x;
    const __hip_bfloat16 *A, *Bm;
    __hip_bfloat16* Cb;
    float sc;
    int rem;
    if (blk < 100) { A = WqT; Bm = WkT; Cb = Bcat; sc = scale; rem = blk; }
    else { A = Wrb; Bm = WvT; Cb = Bcat + 1280 * 1280; sc = 1.f; rem = blk - 100; }
    int tm = rem / 10, tn = rem - tm * 10;

    int t = threadIdx.x;
    int lane = t & 63;
    int w = t >> 6;
    int wm = w >> 1, wn = w & 1;
    int lane15 = lane & 15, lhi = lane >> 4;

    const __hip_bfloat16* Ab = A + (long)tm * 128 * C_;
    const __hip_bfloat16* Bb = Bm + (long)tn * 128 * C_;

    f32x4 acc[4][4];
#pragma unroll
    for (int i = 0; i < 4; ++i)
#pragma unroll
        for (int j = 0; j < 4; ++j) acc[i][j] = (f32x4){0.f, 0.f, 0.f, 0.f};

    int e0 = t * 8;
    int r0 = e0 >> 5;
    int c0e = e0 & 31;

    for (int k0 = 0; k0 < C_; k0 += 32) {
        gload_lds16(Ab + (long)r0 * C_ + k0 + c0e, lA + e0);
        gload_lds16(Ab + (long)(r0 + 64) * C_ + k0 + c0e, lA + 2048 + e0);
        gload_lds16(Bb + (long)r0 * C_ + k0 + c0e, lB + e0);
        gload_lds16(Bb + (long)(r0 + 64) * C_ + k0 + c0e, lB + 2048 + e0);
        __syncthreads();

        short8 af[4], bf[4];
#pragma unroll
        for (int i = 0; i < 4; ++i)
            af[i] = *reinterpret_cast<const short8*>(lA + (wm * 64 + i * 16 + lane15) * 32 + lhi * 8);
#pragma unroll
        for (int j = 0; j < 4; ++j)
            bf[j] = *reinterpret_cast<const short8*>(lB + (wn * 64 + j * 16 + lane15) * 32 + lhi * 8);
#pragma unroll
        for (int i = 0; i < 4; ++i)
#pragma unroll
            for (int j = 0; j < 4; ++j)
                acc[i][j] = __builtin_amdgcn_mfma_f32_16x16x32_bf16(af[i], bf[j], acc[i][j], 0, 0, 0);
        __syncthreads();
    }

#pragma unroll
    for (int i = 0; i < 4; ++i) {
        int gm = tm * 128 + wm * 64 + i * 16 + lhi * 4;
#pragma unroll
        for (int j = 0; j < 4; ++j) {
            int gn = tn * 128 + wn * 64 + j * 16 + lane15;
#pragma unroll
            for (int r = 0; r < 4; ++r)
                Cb[(long)(gm + r) * C_ + gn] = __float2bfloat16(acc[i][j][r] * sc);
        }
    }
}

// ====== final_att: out[b][c][s] = alpha * sum_j Abf[b,s,j]*P[b,c,j] + x[b][c][s] ======
// Per b: M=S (s), N=C (c), K=S (j). Grid: b*20 + tm*10 + tn, 1280 blocks, 256 thr.
__global__ __launch_bounds__(256) void final_att(
    const __hip_bfloat16* __restrict__ Abf, const __hip_bfloat16* __restrict__ P,
    const float* __restrict__ x, const float* __restrict__ alphaPtr,
    float* __restrict__ out) {
    __shared__ __hip_bfloat16 lA[128 * 32];
    __shared__ __hip_bfloat16 lB[128 * 32];

    int blk = blockIdx.x;
    int b = blk / 20;
    int rem = blk - b * 20;
    int tm = rem / 10, tn = rem - tm * 10;  // tm: s-tile (0..1), tn: c-tile (0..9)

    int t = threadIdx.x;
    int lane = t & 63;
    int w = t >> 6;
    int wm = w >> 1, wn = w & 1;
    int lane15 = lane & 15, lhi = lane >> 4;

    const __hip_bfloat16* Ab = Abf + (long)b * (S_ * S_) + (long)tm * 128 * S_;
    const __hip_bfloat16* Bb = P + (long)b * (C_ * S_) + (long)tn * 128 * S_;

    f32x4 acc[4][4];
#pragma unroll
    for (int i = 0; i < 4; ++i)
#pragma unroll
        for (int j = 0; j < 4; ++j) acc[i][j] = (f32x4){0.f, 0.f, 0.f, 0.f};

    int e0 = t * 8;
    int r0 = e0 >> 5;
    int c0e = e0 & 31;

#pragma unroll
    for (int k0 = 0; k0 < S_; k0 += 32) {
        gload_lds16(Ab + (long)r0 * S_ + k0 + c0e, lA + e0);
        gload_lds16(Ab + (long)(r0 + 64) * S_ + k0 + c0e, lA + 2048 + e0);
        gload_lds16(Bb + (long)r0 * S_ + k0 + c0e, lB + e0);
        gload_lds16(Bb + (long)(r0 + 64) * S_ + k0 + c0e, lB + 2048 + e0);
        __syncthreads();

        short8 af[4], bf[4];
#pragma unroll
        for (int i = 0; i < 4; ++i)
            af[i] = *reinterpret_cast<const short8*>(lA + (wm * 64 + i * 16 + lane15) * 32 + lhi * 8);
#pragma unroll
        for (int j = 0; j < 4; ++j)
            bf[j] = *reinterpret_cast<const short8*>(lB + (wn * 64 + j * 16 + lane15) * 32 + lhi * 8);
#pragma unroll
        for (int i = 0; i < 4; ++i)
#pragma unroll
            for (int j = 0; j < 4; ++j)
                acc[i][j] = __builtin_amdgcn_mfma_f32_16x16x32_bf16(af[i], bf[j], acc[i][j], 0, 0, 0);
        __syncthreads();
    }

    // out[b][c][s]: m-index = s, n-index = c; r spans consecutive s -> f32x4
    float alpha = alphaPtr[0];
    long bOff = (long)b * (C_ * S_);
#pragma unroll
    for (int i = 0; i < 4; ++i) {
        int s0 = tm * 128 + wm * 64 + i * 16 + lhi * 4;
#pragma unroll
        for (int j = 0; j < 4; ++j) {
            int c = tn * 128 + wn * 64 + j * 16 + lane15;
            long base = bOff + (long)c * S_ + s0;
            f32x4 xv = *reinterpret_cast<const f32x4*>(x + base);
            f32x4 o;
#pragma unroll
            for (int r = 0; r < 4; ++r) o[r] = alpha * acc[i][j][r] + xv[r];
            *reinterpret_cast<f32x4*>(out + base) = o;
        }
    }
}

extern "C" void kernel_launch(void* const* d_in, const int* in_sizes, int n_in,
                              void* d_out, int out_size, void* d_ws, size_t ws_size,
                              hipStream_t stream) {
    const float* x = (const float*)d_in[0];
    const float* Wk = (const float*)d_in[1];
    const float* Wq = (const float*)d_in[2];
    const float* Wv = (const float*)d_in[3];
    const float* Wr = (const float*)d_in[4];
    const float* alphaPtr = (const float*)d_in[5];

    char* ws = (char*)d_ws;
    size_t off = 0;
    auto alloc = [&](size_t bytes) {
        char* p = ws + off;
        off += (bytes + 255) & ~(size_t)255;
        return p;
    };
    const size_t BSC = (size_t)B_ * S_ * C_;  // 16384*1280
    const size_t CC = (size_t)C_ * C_;

    __hip_bfloat16* xT = (__hip_bfloat16*)alloc(BSC * 2);     // [16384][1280]
    __hip_bfloat16* WqT = (__hip_bfloat16*)alloc(CC * 2);
    __hip_bfloat16* WkT = (__hip_bfloat16*)alloc(CC * 2);
    __hip_bfloat16* WvT = (__hip_bfloat16*)alloc(CC * 2);
    __hip_bfloat16* Wrb = (__hip_bfloat16*)alloc(CC * 2);
    __hip_bfloat16* Bcat = (__hip_bfloat16*)alloc(2 * CC * 2);  // [2560][1280]: Bproj ; Wrv
    __hip_bfloat16* G = (__hip_bfloat16*)alloc(BSC * 2);        // [16384][1280]
    __hip_bfloat16* P = (__hip_bfloat16*)alloc(BSC * 2);        // [B][C][S]
    float* scores = (float*)alloc((size_t)B_ * S_ * S_ * 4);
    __hip_bfloat16* Abf = (__hip_bfloat16*)alloc((size_t)B_ * S_ * S_ * 2);

    const float scale = 1.0f / sqrtf((float)C_);

    // 1) weight transposes -> bf16
    prep_weights<<<dim3(40, 40, 4), dim3(32, 8), 0, stream>>>(Wk, Wq, Wv, Wr,
                                                              WqT, WkT, WvT, Wrb);
    // 2) Bcat = [ scale*(Wq^T Wk)  ;  Wr*Wv ]   (two GEMMs, one dispatch)
    gemm_weights<<<200, 256, 0, stream>>>(WqT, WkT, Wrb, WvT, Bcat, scale);

    // 3) x -> xT [16384][1280] bf16
    transpose_cvt<<<dim3(S_ / 32, C_ / 32, B_), dim3(32, 8), 0, stream>>>(x, xT);

    // 4) projections: G = xT * Bproj^T (row-major), P = xT * Wrv^T (transposed to [B][C][S])
    gemm8p<<<640, 512, 0, stream>>>(xT, Bcat, G, C_, C_, C_, C_, 10, 640, 5, P);

    // 5) scores[b][i][j] = sum_c' G[b,i,c'] * xT[b,j,c']   (scale already folded into G)
    gemm_tn<1><<<B_ * 4, 256, 0, stream>>>(G, (long)S_ * C_, C_,
                                           xT, (long)S_ * C_, C_,
                                           scores, (long)S_ * S_, S_,
                                           C_, 2, 2, 1.0f);
    // 6) softmax over batch axis
    softmax_b<<<256, 256, 0, stream>>>(scores, Abf);

    // 7) out[b][c][s] = alpha * sum_j A[b,s,j] P[b,c,j] + x[b][c][s]
    final_att<<<1280, 256, 0, stream>>>(Abf, P, x, alphaPtr, (float*)d_out);
}

// Round 6
// 423.357 us; speedup vs baseline: 1.4912x; 1.0195x over previous
//
#include <hip/hip_runtime.h>
#include <hip/hip_bf16.h>
#include <cstdint>
#include <cmath>

#define B_ 64
#define C_ 1280
#define S_ 256

typedef __attribute__((ext_vector_type(8))) short short8;
typedef __attribute__((ext_vector_type(4))) float f32x4;

typedef const __attribute__((address_space(1))) char gch;
typedef __attribute__((address_space(3))) char lch;

__device__ __forceinline__ void gload_lds16(const void* g, void* l) {
    __builtin_amdgcn_global_load_lds((gch*)g, (lch*)l, 16, 0, 0);
}

__device__ __forceinline__ unsigned short f2bu(float f) {
    __hip_bfloat16 h = __float2bfloat16(f);
    return *reinterpret_cast<unsigned short*>(&h);
}

// ============ prep_x: x-transpose (blocks 0..20479) + weight prep (20480..26879) ============
// x [B][C][S] fp32 -> xT [B*S][C] bf16 ; Wq/Wk/Wv -> transposed bf16 ; Wr -> bf16 copy
__global__ void prep_x(const float* __restrict__ x, __hip_bfloat16* __restrict__ xT,
                       const float* __restrict__ Wk, const float* __restrict__ Wq,
                       const float* __restrict__ Wv, const float* __restrict__ Wr,
                       __hip_bfloat16* __restrict__ WqT, __hip_bfloat16* __restrict__ WkT,
                       __hip_bfloat16* __restrict__ WvT, __hip_bfloat16* __restrict__ Wrb) {
    __shared__ float tile[32][33];
    int id = blockIdx.x;
    int tx = threadIdx.x, ty = threadIdx.y;
    if (id < 20480) {
        int b = id / 320;
        int rem = id - b * 320;
        int s0 = (rem & 7) * 32, c0 = (rem >> 3) * 32;
        const float* xb = x + (long)b * C_ * S_;
#pragma unroll
        for (int dy = 0; dy < 32; dy += 8)
            tile[ty + dy][tx] = xb[(long)(c0 + ty + dy) * S_ + s0 + tx];
        __syncthreads();
        __hip_bfloat16* xTb = xT + (long)b * S_ * C_;
#pragma unroll
        for (int dy = 0; dy < 32; dy += 8)
            xTb[(long)(s0 + ty + dy) * C_ + c0 + tx] = __float2bfloat16(tile[tx][ty + dy]);
    } else {
        int wid = id - 20480;
        int z = wid / 1600;
        int rem = wid - z * 1600;
        int r0 = (rem / 40) * 32, c0 = (rem - (rem / 40) * 40) * 32;
        const float* src = (z == 0) ? Wq : (z == 1) ? Wk : (z == 2) ? Wv : Wr;
        __hip_bfloat16* dst = (z == 0) ? WqT : (z == 1) ? WkT : (z == 2) ? WvT : Wrb;
        if (z == 3) {
#pragma unroll
            for (int dy = 0; dy < 32; dy += 8) {
                int idx = (r0 + ty + dy) * C_ + c0 + tx;
                dst[idx] = __float2bfloat16(src[idx]);
            }
            return;
        }
#pragma unroll
        for (int dy = 0; dy < 32; dy += 8)
            tile[ty + dy][tx] = src[(long)(r0 + ty + dy) * C_ + c0 + tx];
        __syncthreads();
#pragma unroll
        for (int dy = 0; dy < 32; dy += 8)
            dst[(long)(c0 + ty + dy) * C_ + r0 + tx] = __float2bfloat16(tile[tx][ty + dy]);
    }
}

// ---------------- softmax over batch axis ----------------
__global__ void softmax_b(const float* __restrict__ scores, __hip_bfloat16* __restrict__ Abf) {
    int tid = blockIdx.x * blockDim.x + threadIdx.x;  // 0..65535
    float r[64];
    float mx = -1e30f;
#pragma unroll
    for (int b = 0; b < 64; ++b) {
        r[b] = scores[(long)b * 65536 + tid];
        mx = fmaxf(mx, r[b]);
    }
    float sum = 0.f;
#pragma unroll
    for (int b = 0; b < 64; ++b) {
        r[b] = __expf(r[b] - mx);
        sum += r[b];
    }
    float inv = 1.0f / sum;
#pragma unroll
    for (int b = 0; b < 64; ++b)
        Abf[(long)b * 65536 + tid] = __float2bfloat16(r[b] * inv);
}

// ================= 8-phase 256x256 TN GEMM (BK=64, 512 thr, 8 waves 2x4) =================
// C[m][n] = sum_k A[m][k]*B[n][k].  tn < vTile -> bf16 row-major into Cc;
// tn >= vTile -> output written transposed to Vb[b(tm)][c][s] bf16 (the P projection).

#define PH_TOP()                                                \
    do {                                                        \
        __builtin_amdgcn_sched_barrier(0);                      \
        __builtin_amdgcn_s_barrier();                           \
        asm volatile("s_waitcnt lgkmcnt(0)" ::: "memory");      \
        __builtin_amdgcn_sched_barrier(0);                      \
        __builtin_amdgcn_s_setprio(1);                          \
    } while (0)

#define PH_BOT()                                                \
    do {                                                        \
        __builtin_amdgcn_s_setprio(0);                          \
        __builtin_amdgcn_sched_barrier(0);                      \
        __builtin_amdgcn_s_barrier();                           \
    } while (0)

#define PH_BOT_WAIT(LAST_)                                          \
    do {                                                            \
        __builtin_amdgcn_s_setprio(0);                              \
        __builtin_amdgcn_sched_barrier(0);                          \
        if (LAST_) asm volatile("s_waitcnt vmcnt(0)" ::: "memory"); \
        else       asm volatile("s_waitcnt vmcnt(2)" ::: "memory"); \
        __builtin_amdgcn_s_barrier();                               \
    } while (0)

#define MFMA_Q(MO, NO, BFV)                                                                        \
    _Pragma("unroll") for (int m = 0; m < 4; ++m) {                                                \
        _Pragma("unroll") for (int n = 0; n < 2; ++n) {                                            \
            acc[m + MO][n + NO] = __builtin_amdgcn_mfma_f32_16x16x32_bf16(                         \
                af[m][0], BFV[n][0], acc[m + MO][n + NO], 0, 0, 0);                                \
            acc[m + MO][n + NO] = __builtin_amdgcn_mfma_f32_16x16x32_bf16(                         \
                af[m][1], BFV[n][1], acc[m + MO][n + NO], 0, 0, 0);                                \
        }                                                                                          \
    }

#define LOAD_A(SLOT, RO)                                  \
    _Pragma("unroll") for (int m = 0; m < 4; ++m) {       \
        af[m][0] = RD(SLOT, (RO) + m * 16 + l15, 0);      \
        af[m][1] = RD(SLOT, (RO) + m * 16 + l15, 1);      \
    }

#define LOAD_B(SLOT, BFV, NO)                                    \
    _Pragma("unroll") for (int n = 0; n < 2; ++n) {              \
        BFV[n][0] = RD(SLOT, rB0 + ((NO) + n) * 16 + l15, 0);    \
        BFV[n][1] = RD(SLOT, rB0 + ((NO) + n) * 16 + l15, 1);    \
    }

__global__ __launch_bounds__(512, 2) void gemm8p(
    const __hip_bfloat16* __restrict__ A, const __hip_bfloat16* __restrict__ Bm,
    __hip_bfloat16* __restrict__ Cc, int lda, int ldb, int ldc,
    int Kd, int tilesN, int nwg, int vTile,
    __hip_bfloat16* __restrict__ Vb) {
    __shared__ char lds[131072];

    int bid = blockIdx.x;
    int cpx = nwg >> 3;
    int swz = (bid & 7) * cpx + (bid >> 3);
    int tm = swz / tilesN, tn = swz - tm * tilesN;

    int t = threadIdx.x;
    int lane = t & 63, w = t >> 6;
    int wm = w >> 2, wn = w & 3;
    int l15 = lane & 15, lhi = lane >> 4;
    int rB0 = (wn & 1) * 64;
    const int sA0 = wm, sB0 = 2 + (wn >> 1);
    const int sA1 = 4 + wm, sB1 = 6 + (wn >> 1);

    const __hip_bfloat16* aT = A + (long)tm * 256 * lda;
    const __hip_bfloat16* bT = Bm + (long)tn * 256 * ldb;

    int srow = t >> 3;
    int sc = ((t & 7) ^ (srow & 7)) * 8;
    const __hip_bfloat16* stA = aT + (long)srow * lda + sc;
    const __hip_bfloat16* stB = bT + (long)srow * ldb + sc;

    auto STAGE = [&](int kt, int j) {
        const __hip_bfloat16* p;
        long ldg;
        if (j < 2) { p = stA + (long)j * 128 * lda + kt * 64; ldg = lda; }
        else       { p = stB + (long)(j - 2) * 128 * ldb + kt * 64; ldg = ldb; }
        char* slot = lds + (((kt & 1) * 4 + j) << 14);
        gload_lds16(p, slot + t * 16);
        gload_lds16(p + 64 * ldg, slot + t * 16 + 8192);
    };

    auto RD = [&](int slotIdx, int row, int kk) -> short8 {
        const char* p = lds + (slotIdx << 14) + row * 128 +
                        ((((kk << 2) + lhi) ^ (row & 7)) << 4);
        return *reinterpret_cast<const short8*>(p);
    };

    f32x4 acc[8][4];
#pragma unroll
    for (int i = 0; i < 8; ++i)
#pragma unroll
        for (int j = 0; j < 4; ++j) acc[i][j] = (f32x4){0.f, 0.f, 0.f, 0.f};

    short8 af[4][2], b0v[2][2], b1v[2][2];

    STAGE(0, 0); STAGE(0, 1); STAGE(0, 2); STAGE(0, 3); STAGE(1, 0);
    asm volatile("s_waitcnt vmcnt(2)" ::: "memory");
    __builtin_amdgcn_s_barrier();
    __builtin_amdgcn_sched_barrier(0);

    const int NTH = Kd >> 7;
    for (int i = 0; i < NTH; ++i) {
        const bool last = (i == NTH - 1);
        const int kt0 = 2 * i, kt1 = 2 * i + 1;

        LOAD_A(sA0, 0)
        LOAD_B(sB0, b0v, 0)
        STAGE(kt1, 1);
        PH_TOP();
        MFMA_Q(0, 0, b0v)
        PH_BOT();

        LOAD_B(sB0, b1v, 2)
        STAGE(kt1, 2);
        PH_TOP();
        MFMA_Q(0, 2, b1v)
        PH_BOT();

        LOAD_A(sA0, 64)
        STAGE(kt1, 3);
        PH_TOP();
        MFMA_Q(4, 2, b1v)
        PH_BOT();

        if (!last) STAGE(kt0 + 2, 0);
        PH_TOP();
        MFMA_Q(4, 0, b0v)
        PH_BOT_WAIT(last);

        LOAD_A(sA1, 0)
        LOAD_B(sB1, b0v, 0)
        if (!last) STAGE(kt0 + 2, 1);
        PH_TOP();
        MFMA_Q(0, 0, b0v)
        PH_BOT();

        LOAD_B(sB1, b1v, 2)
        if (!last) STAGE(kt0 + 2, 2);
        PH_TOP();
        MFMA_Q(0, 2, b1v)
        PH_BOT();

        LOAD_A(sA1, 64)
        if (!last) STAGE(kt0 + 2, 3);
        PH_TOP();
        MFMA_Q(4, 2, b1v)
        PH_BOT();

        if (!last) STAGE(kt0 + 3, 0);
        PH_TOP();
        MFMA_Q(4, 0, b0v)
        __builtin_amdgcn_s_setprio(0);
        __builtin_amdgcn_sched_barrier(0);
        if (!last) asm volatile("s_waitcnt vmcnt(2)" ::: "memory");
        __builtin_amdgcn_s_barrier();
    }

    // epilogue: D frag (m,n): col = l15 (B-row), row = lhi*4 + r (A-row)
    if (tn < vTile) {
        long crow0 = (long)tm * 256 + wm * 128;
        int cc0 = tn * 256 + wn * 64;
#pragma unroll
        for (int m = 0; m < 8; ++m) {
            long gm = crow0 + m * 16 + lhi * 4;
#pragma unroll
            for (int n = 0; n < 4; ++n) {
                int gn = cc0 + n * 16 + l15;
#pragma unroll
                for (int r = 0; r < 4; ++r)
                    Cc[(gm + r) * ldc + gn] = __float2bfloat16(acc[m][n][r]);
            }
        }
    } else {
        // P region: write transposed to Vb[b][c][s], b = tm
        unsigned short* Vus = (unsigned short*)Vb;
        int cb0 = (tn - vTile) * 256 + wn * 64;
#pragma unroll
        for (int m = 0; m < 8; ++m) {
            int s0 = wm * 128 + m * 16 + lhi * 4;
#pragma unroll
            for (int n = 0; n < 4; ++n) {
                int c = cb0 + n * 16 + l15;
                ushort4 pk;
                pk.x = f2bu(acc[m][n][0]);
                pk.y = f2bu(acc[m][n][1]);
                pk.z = f2bu(acc[m][n][2]);
                pk.w = f2bu(acc[m][n][3]);
                *reinterpret_cast<ushort4*>(&Vus[((long)(tm * 1280 + c) << 8) + s0]) = pk;
            }
        }
    }
}

// ====== gemm_scores: prefetched dbuf 128x128, swizzled [128][32] tiles ======
// scores[b][i][j] = scale * sum_c G[b,i,c] * xT[b,j,c]; grid 256 = b*4 + tm*2 + tn
__global__ __launch_bounds__(256) void gemm_scores(
    const __hip_bfloat16* __restrict__ G, const __hip_bfloat16* __restrict__ xT,
    float* __restrict__ scores, float scale) {
    __shared__ __hip_bfloat16 lA[2][4096];
    __shared__ __hip_bfloat16 lB[2][4096];

    int blk = blockIdx.x;
    int b = blk >> 2, tm = (blk >> 1) & 1, tn = blk & 1;
    int t = threadIdx.x, lane = t & 63, w = t >> 6;
    int wm = w >> 1, wn = w & 1;
    int l15 = lane & 15, lhi = lane >> 4;
    int kx = (lhi ^ (l15 & 3)) << 4;  // lane-constant swizzled chunk byte offset

    const __hip_bfloat16* Ab = G + (long)b * (S_ * C_) + (long)tm * 128 * C_;
    const __hip_bfloat16* Bb = xT + (long)b * (S_ * C_) + (long)tn * 128 * C_;

    int arow = t >> 2;
    int acol = ((t & 3) ^ (arow & 3)) * 8;  // inverse-swizzled source chunk

    auto STAGE = [&](int k0, int buf) {
        gload_lds16(Ab + (long)arow * C_ + k0 + acol, (char*)lA[buf] + t * 16);
        gload_lds16(Ab + (long)(arow + 64) * C_ + k0 + acol, (char*)lA[buf] + t * 16 + 4096);
        gload_lds16(Bb + (long)arow * C_ + k0 + acol, (char*)lB[buf] + t * 16);
        gload_lds16(Bb + (long)(arow + 64) * C_ + k0 + acol, (char*)lB[buf] + t * 16 + 4096);
    };

    f32x4 acc[4][4];
#pragma unroll
    for (int i = 0; i < 4; ++i)
#pragma unroll
        for (int j = 0; j < 4; ++j) acc[i][j] = (f32x4){0.f, 0.f, 0.f, 0.f};

    STAGE(0, 0);
    __syncthreads();

#pragma unroll 2
    for (int k = 0; k < 40; ++k) {
        int cur = k & 1;
        if (k < 39) STAGE((k + 1) * 32, cur ^ 1);
        short8 af[4], bf[4];
#pragma unroll
        for (int i = 0; i < 4; ++i)
            af[i] = *reinterpret_cast<const short8*>(
                (const char*)lA[cur] + (wm * 64 + i * 16 + l15) * 64 + kx);
#pragma unroll
        for (int j = 0; j < 4; ++j)
            bf[j] = *reinterpret_cast<const short8*>(
                (const char*)lB[cur] + (wn * 64 + j * 16 + l15) * 64 + kx);
#pragma unroll
        for (int i = 0; i < 4; ++i)
#pragma unroll
            for (int j = 0; j < 4; ++j)
                acc[i][j] = __builtin_amdgcn_mfma_f32_16x16x32_bf16(af[i], bf[j], acc[i][j], 0, 0, 0);
        __syncthreads();
    }

    float* Cb = scores + (long)b * 65536;
#pragma unroll
    for (int i = 0; i < 4; ++i) {
        int gm = tm * 128 + wm * 64 + i * 16 + lhi * 4;
#pragma unroll
        for (int j = 0; j < 4; ++j) {
            int gn = tn * 128 + wn * 64 + j * 16 + l15;
#pragma unroll
            for (int r = 0; r < 4; ++r)
                Cb[(long)(gm + r) * 256 + gn] = acc[i][j][r] * scale;
        }
    }
}

// ====== gemm_weights: two 1280^3 TN GEMMs, prefetched dbuf, one dispatch (200 blocks) ======
// blk<100: Bcat[0..1280) = scale * WqT x WkT ; blk>=100: Bcat[1280..2560) = Wrb x WvT
__global__ __launch_bounds__(256) void gemm_weights(
    const __hip_bfloat16* __restrict__ WqT, const __hip_bfloat16* __restrict__ WkT,
    const __hip_bfloat16* __restrict__ Wrb, const __hip_bfloat16* __restrict__ WvT,
    __hip_bfloat16* __restrict__ Bcat, float scale) {
    __shared__ __hip_bfloat16 lA[2][4096];
    __shared__ __hip_bfloat16 lB[2][4096];

    int blk = blockIdx.x;
    const __hip_bfloat16 *A, *Bm;
    __hip_bfloat16* Cb;
    float sc;
    int rem;
    if (blk < 100) { A = WqT; Bm = WkT; Cb = Bcat; sc = scale; rem = blk; }
    else { A = Wrb; Bm = WvT; Cb = Bcat + 1280 * 1280; sc = 1.f; rem = blk - 100; }
    int tm = rem / 10, tn = rem - tm * 10;

    int t = threadIdx.x, lane = t & 63, w = t >> 6;
    int wm = w >> 1, wn = w & 1;
    int l15 = lane & 15, lhi = lane >> 4;
    int kx = (lhi ^ (l15 & 3)) << 4;

    const __hip_bfloat16* Ab = A + (long)tm * 128 * C_;
    const __hip_bfloat16* Bb = Bm + (long)tn * 128 * C_;

    int arow = t >> 2;
    int acol = ((t & 3) ^ (arow & 3)) * 8;

    auto STAGE = [&](int k0, int buf) {
        gload_lds16(Ab + (long)arow * C_ + k0 + acol, (char*)lA[buf] + t * 16);
        gload_lds16(Ab + (long)(arow + 64) * C_ + k0 + acol, (char*)lA[buf] + t * 16 + 4096);
        gload_lds16(Bb + (long)arow * C_ + k0 + acol, (char*)lB[buf] + t * 16);
        gload_lds16(Bb + (long)(arow + 64) * C_ + k0 + acol, (char*)lB[buf] + t * 16 + 4096);
    };

    f32x4 acc[4][4];
#pragma unroll
    for (int i = 0; i < 4; ++i)
#pragma unroll
        for (int j = 0; j < 4; ++j) acc[i][j] = (f32x4){0.f, 0.f, 0.f, 0.f};

    STAGE(0, 0);
    __syncthreads();

#pragma unroll 2
    for (int k = 0; k < 40; ++k) {
        int cur = k & 1;
        if (k < 39) STAGE((k + 1) * 32, cur ^ 1);
        short8 af[4], bf[4];
#pragma unroll
        for (int i = 0; i < 4; ++i)
            af[i] = *reinterpret_cast<const short8*>(
                (const char*)lA[cur] + (wm * 64 + i * 16 + l15) * 64 + kx);
#pragma unroll
        for (int j = 0; j < 4; ++j)
            bf[j] = *reinterpret_cast<const short8*>(
                (const char*)lB[cur] + (wn * 64 + j * 16 + l15) * 64 + kx);
#pragma unroll
        for (int i = 0; i < 4; ++i)
#pragma unroll
            for (int j = 0; j < 4; ++j)
                acc[i][j] = __builtin_amdgcn_mfma_f32_16x16x32_bf16(af[i], bf[j], acc[i][j], 0, 0, 0);
        __syncthreads();
    }

#pragma unroll
    for (int i = 0; i < 4; ++i) {
        int gm = tm * 128 + wm * 64 + i * 16 + lhi * 4;
#pragma unroll
        for (int j = 0; j < 4; ++j) {
            int gn = tn * 128 + wn * 64 + j * 16 + l15;
#pragma unroll
            for (int r = 0; r < 4; ++r)
                Cb[(long)(gm + r) * C_ + gn] = __float2bfloat16(acc[i][j][r] * sc);
        }
    }
}

// ====== final_att2: out[b][c][s] = alpha * sum_j Abf[b,s,j]*P[b,c,j] + x[b][c][s] ======
// 128(s) x 256(c) tiles, prefetched dbuf, swizzled. Grid 640 = b*10 + tm*5 + tnp.
__global__ __launch_bounds__(256, 2) void final_att2(
    const __hip_bfloat16* __restrict__ Abf, const __hip_bfloat16* __restrict__ P,
    const float* __restrict__ x, const float* __restrict__ alphaPtr,
    float* __restrict__ out) {
    __shared__ __hip_bfloat16 lA[2][4096];  // 128 x 32
    __shared__ __hip_bfloat16 lB[2][8192];  // 256 x 32

    int blk = blockIdx.x;
    int b = blk / 10;
    int rem = blk - b * 10;
    int tm = rem / 5, tnp = rem - tm * 5;

    int t = threadIdx.x, lane = t & 63, w = t >> 6;
    int wm = w >> 1, wn = w & 1;
    int l15 = lane & 15, lhi = lane >> 4;
    int kx = (lhi ^ (l15 & 3)) << 4;

    const __hip_bfloat16* Ab = Abf + (long)b * 65536 + (long)tm * 128 * 256;
    const __hip_bfloat16* Bb = P + (long)b * (C_ * S_) + (long)tnp * 256 * 256;

    int arow = t >> 2;
    int acol = ((t & 3) ^ (arow & 3)) * 8;

    auto STAGE = [&](int k0, int buf) {
        gload_lds16(Ab + (long)arow * 256 + k0 + acol, (char*)lA[buf] + t * 16);
        gload_lds16(Ab + (long)(arow + 64) * 256 + k0 + acol, (char*)lA[buf] + t * 16 + 4096);
#pragma unroll
        for (int j = 0; j < 4; ++j)
            gload_lds16(Bb + (long)(arow + j * 64) * 256 + k0 + acol,
                        (char*)lB[buf] + t * 16 + j * 4096);
    };

    f32x4 acc[4][8];
#pragma unroll
    for (int i = 0; i < 4; ++i)
#pragma unroll
        for (int n = 0; n < 8; ++n) acc[i][n] = (f32x4){0.f, 0.f, 0.f, 0.f};

    STAGE(0, 0);
    __syncthreads();

#pragma unroll
    for (int k = 0; k < 8; ++k) {
        int cur = k & 1;
        if (k < 7) STAGE((k + 1) * 32, cur ^ 1);
        short8 af[4], bf[8];
#pragma unroll
        for (int i = 0; i < 4; ++i)
            af[i] = *reinterpret_cast<const short8*>(
                (const char*)lA[cur] + (wm * 64 + i * 16 + l15) * 64 + kx);
#pragma unroll
        for (int n = 0; n < 8; ++n)
            bf[n] = *reinterpret_cast<const short8*>(
                (const char*)lB[cur] + (wn * 128 + n * 16 + l15) * 64 + kx);
#pragma unroll
        for (int i = 0; i < 4; ++i)
#pragma unroll
            for (int n = 0; n < 8; ++n)
                acc[i][n] = __builtin_amdgcn_mfma_f32_16x16x32_bf16(af[i], bf[n], acc[i][n], 0, 0, 0);
        __syncthreads();
    }

    float alpha = alphaPtr[0];
    long bOff = (long)b * (C_ * S_);
#pragma unroll
    for (int i = 0; i < 4; ++i) {
        int s0 = tm * 128 + wm * 64 + i * 16 + lhi * 4;
#pragma unroll
        for (int n = 0; n < 8; ++n) {
            int c = tnp * 256 + wn * 128 + n * 16 + l15;
            long base = bOff + (long)c * 256 + s0;
            f32x4 xv = *reinterpret_cast<const f32x4*>(x + base);
            f32x4 o;
#pragma unroll
            for (int r = 0; r < 4; ++r) o[r] = alpha * acc[i][n][r] + xv[r];
            *reinterpret_cast<f32x4*>(out + base) = o;
        }
    }
}

extern "C" void kernel_launch(void* const* d_in, const int* in_sizes, int n_in,
                              void* d_out, int out_size, void* d_ws, size_t ws_size,
                              hipStream_t stream) {
    const float* x = (const float*)d_in[0];
    const float* Wk = (const float*)d_in[1];
    const float* Wq = (const float*)d_in[2];
    const float* Wv = (const float*)d_in[3];
    const float* Wr = (const float*)d_in[4];
    const float* alphaPtr = (const float*)d_in[5];

    char* ws = (char*)d_ws;
    size_t off = 0;
    auto alloc = [&](size_t bytes) {
        char* p = ws + off;
        off += (bytes + 255) & ~(size_t)255;
        return p;
    };
    const size_t BSC = (size_t)B_ * S_ * C_;  // 16384*1280
    const size_t CC = (size_t)C_ * C_;

    __hip_bfloat16* xT = (__hip_bfloat16*)alloc(BSC * 2);  // [16384][1280]
    __hip_bfloat16* WqT = (__hip_bfloat16*)alloc(CC * 2);
    __hip_bfloat16* WkT = (__hip_bfloat16*)alloc(CC * 2);
    __hip_bfloat16* WvT = (__hip_bfloat16*)alloc(CC * 2);
    __hip_bfloat16* Wrb = (__hip_bfloat16*)alloc(CC * 2);
    __hip_bfloat16* Bcat = (__hip_bfloat16*)alloc(2 * CC * 2);  // [2560][1280]: Bproj ; Wrv
    __hip_bfloat16* G = (__hip_bfloat16*)alloc(BSC * 2);        // [16384][1280]
    __hip_bfloat16* P = (__hip_bfloat16*)alloc(BSC * 2);        // [B][C][S]
    float* scores = (float*)alloc((size_t)B_ * S_ * S_ * 4);
    __hip_bfloat16* Abf = (__hip_bfloat16*)alloc((size_t)B_ * S_ * S_ * 2);

    const float scale = 1.0f / sqrtf((float)C_);

    // 1) x -> xT bf16 + weight transposes (one dispatch)
    prep_x<<<26880, dim3(32, 8), 0, stream>>>(x, xT, Wk, Wq, Wv, Wr, WqT, WkT, WvT, Wrb);

    // 2) Bcat = [ scale*(Wq^T Wk) ; Wr*Wv ]
    gemm_weights<<<200, 256, 0, stream>>>(WqT, WkT, Wrb, WvT, Bcat, scale);

    // 3) projections: G = xT * Bproj^T (row-major), P = xT * Wrv^T (transposed to [B][C][S])
    gemm8p<<<640, 512, 0, stream>>>(xT, Bcat, G, C_, C_, C_, C_, 10, 640, 5, P);

    // 4) scores[b][i][j] = sum_c G[b,i,c] * xT[b,j,c]  (scale folded into Bproj)
    gemm_scores<<<256, 256, 0, stream>>>(G, xT, scores, 1.0f);

    // 5) softmax over batch axis
    softmax_b<<<256, 256, 0, stream>>>(scores, Abf);

    // 6) out[b][c][s] = alpha * sum_j A[b,s,j] P[b,c,j] + x[b][c][s]
    final_att2<<<640, 256, 0, stream>>>(Abf, P, x, alphaPtr, (float*)d_out);
}